// Round 3
// baseline (1367.259 us; speedup 1.0000x reference)
//
#include <hip/hip_runtime.h>

#define N_NODES 50000
#define N_EDGES 800000
#define DIM 128
#define N_REL 86
#define BATCH 2048

static __device__ __forceinline__ float wave_reduce(float v) {
  #pragma unroll
  for (int off = 32; off > 0; off >>= 1) v += __shfl_xor(v, off, 64);
  return v;
}

// ---------------- degree / CSR build ----------------

__global__ __launch_bounds__(256) void k_count(const int* __restrict__ dst, int* __restrict__ cnt) {
  int i = blockIdx.x * 256 + threadIdx.x;
  if (i < N_EDGES) atomicAdd(&cnt[dst[i]], 1);
}

__global__ __launch_bounds__(256) void k_dinv(const int* __restrict__ cnt, float* __restrict__ dinv) {
  int i = blockIdx.x * 256 + threadIdx.x;
  if (i < N_NODES) dinv[i] = rsqrtf((float)(cnt[i] + 1));
}

__global__ __launch_bounds__(256) void k_scan_reduce(const int* __restrict__ cnt, int* __restrict__ bsum) {
  __shared__ int sd[256];
  int base = blockIdx.x * 1024;
  int t = threadIdx.x;
  int s = 0;
  #pragma unroll
  for (int i = 0; i < 4; ++i) {
    int idx = base + t * 4 + i;
    if (idx < N_NODES) s += cnt[idx];
  }
  sd[t] = s; __syncthreads();
  for (int off = 128; off > 0; off >>= 1) {
    if (t < off) sd[t] += sd[t + off];
    __syncthreads();
  }
  if (t == 0) bsum[blockIdx.x] = sd[0];
}

__global__ void k_scan_bsum(int* __restrict__ bsum, int* __restrict__ rowptr_end, int nb) {
  if (threadIdx.x == 0 && blockIdx.x == 0) {
    int acc = 0;
    for (int i = 0; i < nb; ++i) { int v = bsum[i]; bsum[i] = acc; acc += v; }
    *rowptr_end = acc;   // rowptr[N_NODES] == N_EDGES
  }
}

__global__ __launch_bounds__(256) void k_scan_scatter(const int* __restrict__ cnt, const int* __restrict__ bsum,
                                                      int* __restrict__ rowptr) {
  __shared__ int sd[256];
  int base = blockIdx.x * 1024;
  int t = threadIdx.x;
  int v[4]; int s = 0;
  #pragma unroll
  for (int i = 0; i < 4; ++i) {
    int idx = base + t * 4 + i;
    v[i] = (idx < N_NODES) ? cnt[idx] : 0;
    s += v[i];
  }
  sd[t] = s; __syncthreads();
  // inclusive Hillis-Steele scan
  for (int off = 1; off < 256; off <<= 1) {
    int y = (t >= off) ? sd[t - off] : 0;
    __syncthreads();
    sd[t] += y;
    __syncthreads();
  }
  int pre = bsum[blockIdx.x] + sd[t] - s;  // exclusive prefix
  #pragma unroll
  for (int i = 0; i < 4; ++i) {
    int idx = base + t * 4 + i;
    if (idx < N_NODES) rowptr[idx] = pre;
    pre += v[i];
  }
}

__global__ __launch_bounds__(256) void k_fill(const int* __restrict__ src, const int* __restrict__ dst,
                                              const int* __restrict__ rowptr, int* __restrict__ cursor,
                                              int* __restrict__ esrc) {
  int i = blockIdx.x * 256 + threadIdx.x;
  if (i >= N_EDGES) return;
  int d = dst[i];
  int pos = atomicAdd(&cursor[d], 1);
  esrc[rowptr[d] + pos] = src[i];
}

// ---------------- dense: out[nrows,128] = x[nrows,128] @ W[128,128] ----------------
// W staged in LDS as float2 pairs (W[k][j], W[k][j+64]); each wave computes 2 rows x 2 cols.

__global__ __launch_bounds__(256) void k_gemm128(const float* __restrict__ x, const float* __restrict__ W,
                                                 float* __restrict__ out, int nrows) {
  __shared__ float2 Wl[DIM * 64];
  for (int i = threadIdx.x; i < DIM * 64; i += 256) {
    int k = i >> 6, j = i & 63;
    Wl[i] = make_float2(W[k * DIM + j], W[k * DIM + j + 64]);
  }
  __syncthreads();
  int wave = threadIdx.x >> 6, lane = threadIdx.x & 63;
  int row0 = blockIdx.x * 64;
  for (int rp = wave * 2; rp < 64; rp += 8) {
    int r0 = row0 + rp;
    if (r0 >= nrows) break;
    int r1 = r0 + 1;
    bool has1 = (r1 < nrows);
    const float4* xr0 = (const float4*)(x + (size_t)r0 * DIM);
    const float4* xr1 = has1 ? (const float4*)(x + (size_t)r1 * DIM) : xr0;
    float a00 = 0.f, a01 = 0.f, a10 = 0.f, a11 = 0.f;
    #pragma unroll
    for (int k4 = 0; k4 < 32; ++k4) {
      float4 v0 = xr0[k4];
      float4 v1 = xr1[k4];
      float2 w;
      w = Wl[(k4 * 4 + 0) * 64 + lane]; a00 += v0.x * w.x; a01 += v0.x * w.y; a10 += v1.x * w.x; a11 += v1.x * w.y;
      w = Wl[(k4 * 4 + 1) * 64 + lane]; a00 += v0.y * w.x; a01 += v0.y * w.y; a10 += v1.y * w.x; a11 += v1.y * w.y;
      w = Wl[(k4 * 4 + 2) * 64 + lane]; a00 += v0.z * w.x; a01 += v0.z * w.y; a10 += v1.z * w.x; a11 += v1.z * w.y;
      w = Wl[(k4 * 4 + 3) * 64 + lane]; a00 += v0.w * w.x; a01 += v0.w * w.y; a10 += v1.w * w.x; a11 += v1.w * w.y;
    }
    out[(size_t)r0 * DIM + lane] = a00;
    out[(size_t)r0 * DIM + lane + 64] = a01;
    if (has1) {
      out[(size_t)r1 * DIM + lane] = a10;
      out[(size_t)r1 * DIM + lane + 64] = a11;
    }
  }
}

// ---------------- GCN aggregate: out[d] = dinv[d]*(sum_in dinv[s]h[s] + dinv[d]h[d]) + b ----------------

__global__ __launch_bounds__(256) void k_agg(const float* __restrict__ h, const int* __restrict__ rowptr,
                                             const int* __restrict__ esrc, const float* __restrict__ dinv,
                                             const float* __restrict__ bias, float* __restrict__ out) {
  int node = blockIdx.x * 4 + (threadIdx.x >> 6);
  if (node >= N_NODES) return;
  int lane = threadIdx.x & 63;
  const float2* h2 = (const float2*)h;
  float di = dinv[node];
  float2 hv = h2[(size_t)node * 64 + lane];
  float ax = di * hv.x, ay = di * hv.y;
  int e = rowptr[node], end = rowptr[node + 1];
  for (; e < end; ++e) {
    int s = esrc[e];
    float ds = dinv[s];
    float2 hs = h2[(size_t)s * 64 + lane];
    ax = fmaf(ds, hs.x, ax);
    ay = fmaf(ds, hs.y, ay);
  }
  float2 bb = ((const float2*)bias)[lane];
  ((float2*)out)[(size_t)node * 64 + lane] = make_float2(fmaf(di, ax, bb.x), fmaf(di, ay, bb.y));
}

// ---------------- gather head/tail rows ----------------

__global__ __launch_bounds__(128) void k_gather(const float* __restrict__ x, const int* __restrict__ head,
                                                const int* __restrict__ tail, float* __restrict__ he,
                                                float* __restrict__ te) {
  int b = blockIdx.x;
  int t = threadIdx.x;
  int lane = t & 63;
  const float2* x2 = (const float2*)x;
  if (t < 64) ((float2*)he)[b * 64 + lane] = x2[(size_t)head[b] * 64 + lane];
  else        ((float2*)te)[b * 64 + lane] = x2[(size_t)tail[b] * 64 + lane];
}

// ---------------- Q_r = T_r @ Rel_r^T (rotate-swizzled LDS to kill bank conflicts) ----------------

__global__ __launch_bounds__(256) void k_qmat2(const float* __restrict__ T, const float* __restrict__ Rel,
                                               float* __restrict__ Q) {
  __shared__ float Rl[DIM * DIM];  // Rl[e*128 + ((f+e)&127)] = Rel_r[e,f]
  int r = blockIdx.x;
  const float* Rr = Rel + (size_t)r * DIM * DIM;
  const float* Tr = T + (size_t)r * DIM * DIM;
  float* Qr = Q + (size_t)r * DIM * DIM;
  for (int i = threadIdx.x; i < DIM * DIM; i += 256) {
    int e = i >> 7, f = i & 127;
    Rl[e * DIM + ((f + e) & 127)] = Rr[i];
  }
  __syncthreads();
  int wave = threadIdx.x >> 6, lane = threadIdx.x & 63;
  for (int d = wave; d < DIM; d += 4) {
    const float4* trow = (const float4*)(Tr + d * DIM);
    int e0 = lane, e1 = lane + 64;
    float a0 = 0.f, a1 = 0.f;
    #pragma unroll
    for (int f4 = 0; f4 < 32; ++f4) {
      float4 tv = trow[f4];
      a0 += tv.x * Rl[e0 * DIM + ((4 * f4 + 0 + e0) & 127)];
      a1 += tv.x * Rl[e1 * DIM + ((4 * f4 + 0 + e1) & 127)];
      a0 += tv.y * Rl[e0 * DIM + ((4 * f4 + 1 + e0) & 127)];
      a1 += tv.y * Rl[e1 * DIM + ((4 * f4 + 1 + e1) & 127)];
      a0 += tv.z * Rl[e0 * DIM + ((4 * f4 + 2 + e0) & 127)];
      a1 += tv.z * Rl[e1 * DIM + ((4 * f4 + 2 + e1) & 127)];
      a0 += tv.w * Rl[e0 * DIM + ((4 * f4 + 3 + e0) & 127)];
      a1 += tv.w * Rl[e1 * DIM + ((4 * f4 + 3 + e1) & 127)];
    }
    Qr[d * DIM + e0] = a0;
    Qr[d * DIM + e1] = a1;
  }
}

// ---------------- predict[b,r] = he_b^T Q_r te_b ----------------
// v00/v01 are dot products against Q columns (lane, lane+64) — so te must be
// read at elements (lane, lane+64), NOT as a contiguous float2 (round-1 bug).

__global__ __launch_bounds__(256) void k_predict(const float* __restrict__ he, const float* __restrict__ te,
                                                 const float* __restrict__ Q, float* __restrict__ out) {
  __shared__ float2 Ql[DIM * 64];  // (Q[d][j], Q[d][j+64])
  int r = blockIdx.y;
  const float* Qr = Q + (size_t)r * DIM * DIM;
  for (int i = threadIdx.x; i < DIM * 64; i += 256) {
    int d = i >> 6, j = i & 63;
    Ql[i] = make_float2(Qr[d * DIM + j], Qr[d * DIM + j + 64]);
  }
  __syncthreads();
  int wave = threadIdx.x >> 6, lane = threadIdx.x & 63;
  int b_base = blockIdx.x * 64 + wave * 16;
  for (int bp = 0; bp < 16; bp += 2) {
    int b0 = b_base + bp, b1 = b0 + 1;
    const float4* h0 = (const float4*)(he + (size_t)b0 * DIM);
    const float4* h1 = (const float4*)(he + (size_t)b1 * DIM);
    float v00 = 0.f, v01 = 0.f, v10 = 0.f, v11 = 0.f;
    #pragma unroll
    for (int d4 = 0; d4 < 32; ++d4) {
      float4 x0 = h0[d4], x1 = h1[d4];
      float2 w;
      w = Ql[(d4 * 4 + 0) * 64 + lane]; v00 += x0.x * w.x; v01 += x0.x * w.y; v10 += x1.x * w.x; v11 += x1.x * w.y;
      w = Ql[(d4 * 4 + 1) * 64 + lane]; v00 += x0.y * w.x; v01 += x0.y * w.y; v10 += x1.y * w.x; v11 += x1.y * w.y;
      w = Ql[(d4 * 4 + 2) * 64 + lane]; v00 += x0.z * w.x; v01 += x0.z * w.y; v10 += x1.z * w.x; v11 += x1.z * w.y;
      w = Ql[(d4 * 4 + 3) * 64 + lane]; v00 += x0.w * w.x; v01 += x0.w * w.y; v10 += x1.w * w.x; v11 += x1.w * w.y;
    }
    float t0x = te[(size_t)b0 * DIM + lane];
    float t0y = te[(size_t)b0 * DIM + lane + 64];
    float t1x = te[(size_t)b1 * DIM + lane];
    float t1y = te[(size_t)b1 * DIM + lane + 64];
    float p0 = v00 * t0x + v01 * t0y;
    float p1 = v10 * t1x + v11 * t1y;
    p0 = wave_reduce(p0);
    p1 = wave_reduce(p1);
    if (lane == 0) {
      out[(size_t)b0 * N_REL + r] = p0;
      out[(size_t)b1 * N_REL + r] = p1;
    }
  }
}

// ---------------- launch ----------------

extern "C" void kernel_launch(void* const* d_in, const int* in_sizes, int n_in,
                              void* d_out, int out_size, void* d_ws, size_t ws_size,
                              hipStream_t stream) {
  (void)in_sizes; (void)n_in; (void)out_size; (void)ws_size;
  const float* init_emb = (const float*)d_in[0];
  const float* W1  = (const float*)d_in[1];
  const float* b1  = (const float*)d_in[2];
  const float* W2  = (const float*)d_in[3];
  const float* b2  = (const float*)d_in[4];
  const float* Rel = (const float*)d_in[5];
  const float* M   = (const float*)d_in[6];
  const int* head  = (const int*)d_in[7];
  const int* tail  = (const int*)d_in[8];
  const int* src   = (const int*)d_in[9];
  const int* dst   = src + N_EDGES;
  float* out = (float*)d_out;

  char* p = (char*)d_ws;
  auto alloc = [&](size_t bytes) { char* q = p; p += (bytes + 511) & ~(size_t)511; return q; };
  int*   cnt    = (int*)alloc((size_t)N_NODES * 4);
  int*   cursor = (int*)alloc((size_t)N_NODES * 4);
  int*   rowptr = (int*)alloc((size_t)(N_NODES + 1) * 4);
  int*   bsum   = (int*)alloc(64 * 4);
  int*   esrc   = (int*)alloc((size_t)N_EDGES * 4);
  float* dinv   = (float*)alloc((size_t)N_NODES * 4);
  float* bufA   = (float*)alloc((size_t)N_NODES * DIM * 4);
  float* bufB   = (float*)alloc((size_t)N_NODES * DIM * 4);
  float* he     = (float*)alloc((size_t)BATCH * DIM * 4);
  float* te     = (float*)alloc((size_t)BATCH * DIM * 4);
  float* T      = (float*)alloc((size_t)N_REL * DIM * DIM * 4);
  float* Q      = (float*)alloc((size_t)N_REL * DIM * DIM * 4);

  hipMemsetAsync(cnt, 0, (size_t)N_NODES * 4, stream);
  hipMemsetAsync(cursor, 0, (size_t)N_NODES * 4, stream);

  k_count<<<(N_EDGES + 255) / 256, 256, 0, stream>>>(dst, cnt);
  k_dinv<<<(N_NODES + 255) / 256, 256, 0, stream>>>(cnt, dinv);
  int nb = (N_NODES + 1023) / 1024;  // 49
  k_scan_reduce<<<nb, 256, 0, stream>>>(cnt, bsum);
  k_scan_bsum<<<1, 64, 0, stream>>>(bsum, rowptr + N_NODES, nb);
  k_scan_scatter<<<nb, 256, 0, stream>>>(cnt, bsum, rowptr);
  k_fill<<<(N_EDGES + 255) / 256, 256, 0, stream>>>(src, dst, rowptr, cursor, esrc);

  // layer 1
  k_gemm128<<<(N_NODES + 63) / 64, 256, 0, stream>>>(init_emb, W1, bufA, N_NODES);
  k_agg<<<(N_NODES + 3) / 4, 256, 0, stream>>>(bufA, rowptr, esrc, dinv, b1, bufB);
  // layer 2
  k_gemm128<<<(N_NODES + 63) / 64, 256, 0, stream>>>(bufB, W2, bufA, N_NODES);
  k_agg<<<(N_NODES + 3) / 4, 256, 0, stream>>>(bufA, rowptr, esrc, dinv, b2, bufB);

  // decoder
  k_gather<<<BATCH, 128, 0, stream>>>(bufB, head, tail, he, te);
  k_gemm128<<<(N_REL * DIM + 63) / 64, 256, 0, stream>>>(Rel, M, T, N_REL * DIM);  // T_r = Rel_r @ M
  k_qmat2<<<N_REL, 256, 0, stream>>>(T, Rel, Q);                                   // Q_r = T_r @ Rel_r^T
  k_predict<<<dim3(BATCH / 64, N_REL), 256, 0, stream>>>(he, te, Q, out);
}

// Round 4
// 864.758 us; speedup vs baseline: 1.5811x; 1.5811x over previous
//
#include <hip/hip_runtime.h>

#define N_NODES 50000
#define N_EDGES 800000
#define DIM 128
#define N_REL 86
#define BATCH 2048

using bf16x8 = __attribute__((ext_vector_type(8))) short;
using f32x4  = __attribute__((ext_vector_type(4))) float;

static __device__ __forceinline__ float wave_reduce(float v) {
  #pragma unroll
  for (int off = 32; off > 0; off >>= 1) v += __shfl_xor(v, off, 64);
  return v;
}

// float -> bf16 round-to-nearest-even (no NaN handling; inputs are finite)
static __device__ __forceinline__ unsigned short f2bf(float f) {
  union { float f; unsigned int i; } v; v.f = f;
  unsigned int x = v.i;
  unsigned int r = x + 0x7FFFu + ((x >> 16) & 1u);
  return (unsigned short)(r >> 16);
}

// ---------------- degree / CSR build ----------------

__global__ __launch_bounds__(256) void k_count(const int* __restrict__ dst, int* __restrict__ cnt) {
  int i = blockIdx.x * 256 + threadIdx.x;
  if (i < N_EDGES) atomicAdd(&cnt[dst[i]], 1);
}

__global__ __launch_bounds__(256) void k_dinv(const int* __restrict__ cnt, float* __restrict__ dinv) {
  int i = blockIdx.x * 256 + threadIdx.x;
  if (i < N_NODES) dinv[i] = rsqrtf((float)(cnt[i] + 1));
}

__global__ __launch_bounds__(256) void k_scan_reduce(const int* __restrict__ cnt, int* __restrict__ bsum) {
  __shared__ int sd[256];
  int base = blockIdx.x * 1024;
  int t = threadIdx.x;
  int s = 0;
  #pragma unroll
  for (int i = 0; i < 4; ++i) {
    int idx = base + t * 4 + i;
    if (idx < N_NODES) s += cnt[idx];
  }
  sd[t] = s; __syncthreads();
  for (int off = 128; off > 0; off >>= 1) {
    if (t < off) sd[t] += sd[t + off];
    __syncthreads();
  }
  if (t == 0) bsum[blockIdx.x] = sd[0];
}

__global__ void k_scan_bsum(int* __restrict__ bsum, int* __restrict__ rowptr_end, int nb) {
  if (threadIdx.x == 0 && blockIdx.x == 0) {
    int acc = 0;
    for (int i = 0; i < nb; ++i) { int v = bsum[i]; bsum[i] = acc; acc += v; }
    *rowptr_end = acc;   // rowptr[N_NODES] == N_EDGES
  }
}

__global__ __launch_bounds__(256) void k_scan_scatter(const int* __restrict__ cnt, const int* __restrict__ bsum,
                                                      int* __restrict__ rowptr) {
  __shared__ int sd[256];
  int base = blockIdx.x * 1024;
  int t = threadIdx.x;
  int v[4]; int s = 0;
  #pragma unroll
  for (int i = 0; i < 4; ++i) {
    int idx = base + t * 4 + i;
    v[i] = (idx < N_NODES) ? cnt[idx] : 0;
    s += v[i];
  }
  sd[t] = s; __syncthreads();
  for (int off = 1; off < 256; off <<= 1) {
    int y = (t >= off) ? sd[t - off] : 0;
    __syncthreads();
    sd[t] += y;
    __syncthreads();
  }
  int pre = bsum[blockIdx.x] + sd[t] - s;  // exclusive prefix
  #pragma unroll
  for (int i = 0; i < 4; ++i) {
    int idx = base + t * 4 + i;
    if (idx < N_NODES) rowptr[idx] = pre;
    pre += v[i];
  }
}

__global__ __launch_bounds__(256) void k_fill(const int* __restrict__ src, const int* __restrict__ dst,
                                              const int* __restrict__ rowptr, int* __restrict__ cursor,
                                              int* __restrict__ esrc) {
  int i = blockIdx.x * 256 + threadIdx.x;
  if (i >= N_EDGES) return;
  int d = dst[i];
  int pos = atomicAdd(&cursor[d], 1);
  esrc[rowptr[d] + pos] = src[i];
}

// ---------------- dense: out[nrows,128] = x[nrows,128] @ W[128,128] ----------------

__global__ __launch_bounds__(256) void k_gemm128(const float* __restrict__ x, const float* __restrict__ W,
                                                 float* __restrict__ out, int nrows) {
  __shared__ float2 Wl[DIM * 64];
  for (int i = threadIdx.x; i < DIM * 64; i += 256) {
    int k = i >> 6, j = i & 63;
    Wl[i] = make_float2(W[k * DIM + j], W[k * DIM + j + 64]);
  }
  __syncthreads();
  int wave = threadIdx.x >> 6, lane = threadIdx.x & 63;
  int row0 = blockIdx.x * 64;
  for (int rp = wave * 2; rp < 64; rp += 8) {
    int r0 = row0 + rp;
    if (r0 >= nrows) break;
    int r1 = r0 + 1;
    bool has1 = (r1 < nrows);
    const float4* xr0 = (const float4*)(x + (size_t)r0 * DIM);
    const float4* xr1 = has1 ? (const float4*)(x + (size_t)r1 * DIM) : xr0;
    float a00 = 0.f, a01 = 0.f, a10 = 0.f, a11 = 0.f;
    #pragma unroll
    for (int k4 = 0; k4 < 32; ++k4) {
      float4 v0 = xr0[k4];
      float4 v1 = xr1[k4];
      float2 w;
      w = Wl[(k4 * 4 + 0) * 64 + lane]; a00 += v0.x * w.x; a01 += v0.x * w.y; a10 += v1.x * w.x; a11 += v1.x * w.y;
      w = Wl[(k4 * 4 + 1) * 64 + lane]; a00 += v0.y * w.x; a01 += v0.y * w.y; a10 += v1.y * w.x; a11 += v1.y * w.y;
      w = Wl[(k4 * 4 + 2) * 64 + lane]; a00 += v0.z * w.x; a01 += v0.z * w.y; a10 += v1.z * w.x; a11 += v1.z * w.y;
      w = Wl[(k4 * 4 + 3) * 64 + lane]; a00 += v0.w * w.x; a01 += v0.w * w.y; a10 += v1.w * w.x; a11 += v1.w * w.y;
    }
    out[(size_t)r0 * DIM + lane] = a00;
    out[(size_t)r0 * DIM + lane + 64] = a01;
    if (has1) {
      out[(size_t)r1 * DIM + lane] = a10;
      out[(size_t)r1 * DIM + lane + 64] = a11;
    }
  }
}

// ---------------- GCN aggregate ----------------

__global__ __launch_bounds__(256) void k_agg(const float* __restrict__ h, const int* __restrict__ rowptr,
                                             const int* __restrict__ esrc, const float* __restrict__ dinv,
                                             const float* __restrict__ bias, float* __restrict__ out) {
  int node = blockIdx.x * 4 + (threadIdx.x >> 6);
  if (node >= N_NODES) return;
  int lane = threadIdx.x & 63;
  const float2* h2 = (const float2*)h;
  float di = dinv[node];
  float2 hv = h2[(size_t)node * 64 + lane];
  float ax = di * hv.x, ay = di * hv.y;
  int e = rowptr[node], end = rowptr[node + 1];
  for (; e < end; ++e) {
    int s = esrc[e];
    float ds = dinv[s];
    float2 hs = h2[(size_t)s * 64 + lane];
    ax = fmaf(ds, hs.x, ax);
    ay = fmaf(ds, hs.y, ay);
  }
  float2 bb = ((const float2*)bias)[lane];
  ((float2*)out)[(size_t)node * 64 + lane] = make_float2(fmaf(di, ax, bb.x), fmaf(di, ay, bb.y));
}

// ---------------- gather head (fp32) / tail (bf16) rows ----------------

__global__ __launch_bounds__(128) void k_gather(const float* __restrict__ x, const int* __restrict__ head,
                                                const int* __restrict__ tail, float* __restrict__ he,
                                                unsigned short* __restrict__ te_bf) {
  int b = blockIdx.x;
  int t = threadIdx.x;
  int lane = t & 63;
  const float2* x2 = (const float2*)x;
  if (t < 64) {
    ((float2*)he)[b * 64 + lane] = x2[(size_t)head[b] * 64 + lane];
  } else {
    float2 v = x2[(size_t)tail[b] * 64 + lane];
    ushort2 o; o.x = f2bf(v.x); o.y = f2bf(v.y);
    ((ushort2*)te_bf)[b * 64 + lane] = o;
  }
}

// ---------------- Q_r = T_r @ Rel_r^T, output bf16 ----------------

__global__ __launch_bounds__(256) void k_qmat2(const float* __restrict__ T, const float* __restrict__ Rel,
                                               unsigned short* __restrict__ Qbf) {
  __shared__ float Rl[DIM * DIM];  // Rl[e*128 + ((f+e)&127)] = Rel_r[e,f]
  int r = blockIdx.x;
  const float* Rr = Rel + (size_t)r * DIM * DIM;
  const float* Tr = T + (size_t)r * DIM * DIM;
  unsigned short* Qr = Qbf + (size_t)r * DIM * DIM;
  for (int i = threadIdx.x; i < DIM * DIM; i += 256) {
    int e = i >> 7, f = i & 127;
    Rl[e * DIM + ((f + e) & 127)] = Rr[i];
  }
  __syncthreads();
  int wave = threadIdx.x >> 6, lane = threadIdx.x & 63;
  for (int d = wave; d < DIM; d += 4) {
    const float4* trow = (const float4*)(Tr + d * DIM);
    int e0 = lane, e1 = lane + 64;
    float a0 = 0.f, a1 = 0.f;
    #pragma unroll
    for (int f4 = 0; f4 < 32; ++f4) {
      float4 tv = trow[f4];
      a0 += tv.x * Rl[e0 * DIM + ((4 * f4 + 0 + e0) & 127)];
      a1 += tv.x * Rl[e1 * DIM + ((4 * f4 + 0 + e1) & 127)];
      a0 += tv.y * Rl[e0 * DIM + ((4 * f4 + 1 + e0) & 127)];
      a1 += tv.y * Rl[e1 * DIM + ((4 * f4 + 1 + e1) & 127)];
      a0 += tv.z * Rl[e0 * DIM + ((4 * f4 + 2 + e0) & 127)];
      a1 += tv.z * Rl[e1 * DIM + ((4 * f4 + 2 + e1) & 127)];
      a0 += tv.w * Rl[e0 * DIM + ((4 * f4 + 3 + e0) & 127)];
      a1 += tv.w * Rl[e1 * DIM + ((4 * f4 + 3 + e1) & 127)];
    }
    Qr[d * DIM + e0] = f2bf(a0);
    Qr[d * DIM + e1] = f2bf(a1);
  }
}

// ---------------- predict via MFMA ----------------
// Z[b,d] = sum_e te[b,e] * Q_r[d,e]  (mfma_f32_16x16x32_bf16: A=te rows, B=Q rows)
// p[b]   = sum_d he[b,d] * Z[b,d]    (he stays fp32; fp32 reduce)
// Block: 4 waves x 32 batches = 128 batches, one relation. LDS: Q_r bf16, row-padded +8.

#define QPAD 136  // 128 + 8 bf16; row stride 272 B == 17*16 B -> 2-way bank alias (free)

__global__ __launch_bounds__(256) void k_predict_mfma(const float* __restrict__ he,
                                                      const unsigned short* __restrict__ te_bf,
                                                      const unsigned short* __restrict__ Qbf,
                                                      float* __restrict__ out) {
  __shared__ __align__(16) unsigned short Qs[DIM * QPAD];
  int r = blockIdx.y;
  const unsigned short* Qr = Qbf + (size_t)r * DIM * DIM;
  // stage Q_r: 2048 chunks of 8 bf16 (16 B)
  for (int i = threadIdx.x; i < DIM * DIM / 8; i += 256) {
    int d = i >> 4, c = (i & 15) * 8;
    uint4 v = ((const uint4*)Qr)[i];
    *(uint4*)(&Qs[d * QPAD + c]) = v;
  }
  __syncthreads();
  int wave = threadIdx.x >> 6, lane = threadIdx.x & 63;
  int l15 = lane & 15, quad = lane >> 4;
  int bbase = blockIdx.x * 128 + wave * 32;

  f32x4 acc[2][8];
  #pragma unroll
  for (int m = 0; m < 2; ++m)
    #pragma unroll
    for (int n = 0; n < 8; ++n) acc[m][n] = f32x4{0.f, 0.f, 0.f, 0.f};

  union U { uint4 u; bf16x8 h; };
  #pragma unroll
  for (int ks = 0; ks < 4; ++ks) {
    int eoff = ks * 32 + quad * 8;
    U a0, a1;
    a0.u = *(const uint4*)(te_bf + (size_t)(bbase + l15) * DIM + eoff);
    a1.u = *(const uint4*)(te_bf + (size_t)(bbase + 16 + l15) * DIM + eoff);
    #pragma unroll
    for (int nt = 0; nt < 8; ++nt) {
      U b; b.u = *(const uint4*)(&Qs[(nt * 16 + l15) * QPAD + eoff]);
      acc[0][nt] = __builtin_amdgcn_mfma_f32_16x16x32_bf16(a0.h, b.h, acc[0][nt], 0, 0, 0);
      acc[1][nt] = __builtin_amdgcn_mfma_f32_16x16x32_bf16(a1.h, b.h, acc[1][nt], 0, 0, 0);
    }
  }

  // p[b] = sum_d he[b,d] * Z[b,d]; Z C-layout: col(d)=lane&15, row(b)=quad*4+reg
  #pragma unroll
  for (int m = 0; m < 2; ++m) {
    #pragma unroll
    for (int reg = 0; reg < 4; ++reg) {
      int b = bbase + m * 16 + quad * 4 + reg;
      float s = 0.f;
      #pragma unroll
      for (int nt = 0; nt < 8; ++nt)
        s += he[(size_t)b * DIM + nt * 16 + l15] * acc[m][nt][reg];
      #pragma unroll
      for (int off = 1; off < 16; off <<= 1) s += __shfl_xor(s, off, 64);
      if (l15 == 0) out[(size_t)b * N_REL + r] = s;
    }
  }
}

// ---------------- launch ----------------

extern "C" void kernel_launch(void* const* d_in, const int* in_sizes, int n_in,
                              void* d_out, int out_size, void* d_ws, size_t ws_size,
                              hipStream_t stream) {
  (void)in_sizes; (void)n_in; (void)out_size; (void)ws_size;
  const float* init_emb = (const float*)d_in[0];
  const float* W1  = (const float*)d_in[1];
  const float* b1  = (const float*)d_in[2];
  const float* W2  = (const float*)d_in[3];
  const float* b2  = (const float*)d_in[4];
  const float* Rel = (const float*)d_in[5];
  const float* M   = (const float*)d_in[6];
  const int* head  = (const int*)d_in[7];
  const int* tail  = (const int*)d_in[8];
  const int* src   = (const int*)d_in[9];
  const int* dst   = src + N_EDGES;
  float* out = (float*)d_out;

  char* p = (char*)d_ws;
  auto alloc = [&](size_t bytes) { char* q = p; p += (bytes + 511) & ~(size_t)511; return q; };
  int*   cnt    = (int*)alloc((size_t)N_NODES * 4);
  int*   cursor = (int*)alloc((size_t)N_NODES * 4);
  int*   rowptr = (int*)alloc((size_t)(N_NODES + 1) * 4);
  int*   bsum   = (int*)alloc(64 * 4);
  int*   esrc   = (int*)alloc((size_t)N_EDGES * 4);
  float* dinv   = (float*)alloc((size_t)N_NODES * 4);
  float* bufA   = (float*)alloc((size_t)N_NODES * DIM * 4);
  float* bufB   = (float*)alloc((size_t)N_NODES * DIM * 4);
  float* he     = (float*)alloc((size_t)BATCH * DIM * 4);
  unsigned short* te_bf = (unsigned short*)alloc((size_t)BATCH * DIM * 2);
  float* T      = (float*)alloc((size_t)N_REL * DIM * DIM * 4);
  unsigned short* Qbf = (unsigned short*)alloc((size_t)N_REL * DIM * DIM * 2);

  hipMemsetAsync(cnt, 0, (size_t)N_NODES * 4, stream);
  hipMemsetAsync(cursor, 0, (size_t)N_NODES * 4, stream);

  k_count<<<(N_EDGES + 255) / 256, 256, 0, stream>>>(dst, cnt);
  k_dinv<<<(N_NODES + 255) / 256, 256, 0, stream>>>(cnt, dinv);
  int nb = (N_NODES + 1023) / 1024;  // 49
  k_scan_reduce<<<nb, 256, 0, stream>>>(cnt, bsum);
  k_scan_bsum<<<1, 64, 0, stream>>>(bsum, rowptr + N_NODES, nb);
  k_scan_scatter<<<nb, 256, 0, stream>>>(cnt, bsum, rowptr);
  k_fill<<<(N_EDGES + 255) / 256, 256, 0, stream>>>(src, dst, rowptr, cursor, esrc);

  // layer 1
  k_gemm128<<<(N_NODES + 63) / 64, 256, 0, stream>>>(init_emb, W1, bufA, N_NODES);
  k_agg<<<(N_NODES + 3) / 4, 256, 0, stream>>>(bufA, rowptr, esrc, dinv, b1, bufB);
  // layer 2
  k_gemm128<<<(N_NODES + 63) / 64, 256, 0, stream>>>(bufB, W2, bufA, N_NODES);
  k_agg<<<(N_NODES + 3) / 4, 256, 0, stream>>>(bufA, rowptr, esrc, dinv, b2, bufB);

  // decoder
  k_gather<<<BATCH, 128, 0, stream>>>(bufB, head, tail, he, te_bf);
  k_gemm128<<<(N_REL * DIM + 63) / 64, 256, 0, stream>>>(Rel, M, T, N_REL * DIM);  // T_r = Rel_r @ M
  k_qmat2<<<N_REL, 256, 0, stream>>>(T, Rel, Qbf);                                 // Q_r = T_r @ Rel_r^T (bf16)
  k_predict_mfma<<<dim3(BATCH / 128, N_REL), 256, 0, stream>>>(he, te_bf, Qbf, out);
}

// Round 5
// 384.493 us; speedup vs baseline: 3.5560x; 2.2491x over previous
//
#include <hip/hip_runtime.h>

#define N_NODES 50000
#define N_EDGES 800000
#define DIM 128
#define N_REL 86
#define BATCH 2048

using bf16x8 = __attribute__((ext_vector_type(8))) short;
using f32x4  = __attribute__((ext_vector_type(4))) float;

// float -> bf16 round-to-nearest-even (finite inputs)
static __device__ __forceinline__ unsigned short f2bf(float f) {
  union { float f; unsigned int i; } v; v.f = f;
  unsigned int x = v.i;
  unsigned int r = x + 0x7FFFu + ((x >> 16) & 1u);
  return (unsigned short)(r >> 16);
}
static __device__ __forceinline__ float bf2f(unsigned short u) {
  union { unsigned int i; float f; } v;
  v.i = ((unsigned int)u) << 16;
  return v.f;
}

// ---------------- degree / CSR build ----------------

__global__ __launch_bounds__(256) void k_count(const int* __restrict__ dst, int* __restrict__ cnt) {
  int i = blockIdx.x * 256 + threadIdx.x;
  if (i < N_EDGES) atomicAdd(&cnt[dst[i]], 1);
}

__global__ __launch_bounds__(256) void k_dinv(const int* __restrict__ cnt, float* __restrict__ dinv) {
  int i = blockIdx.x * 256 + threadIdx.x;
  if (i < N_NODES) dinv[i] = rsqrtf((float)(cnt[i] + 1));
}

__global__ __launch_bounds__(256) void k_scan_reduce(const int* __restrict__ cnt, int* __restrict__ bsum) {
  __shared__ int sd[256];
  int base = blockIdx.x * 1024;
  int t = threadIdx.x;
  int s = 0;
  #pragma unroll
  for (int i = 0; i < 4; ++i) {
    int idx = base + t * 4 + i;
    if (idx < N_NODES) s += cnt[idx];
  }
  sd[t] = s; __syncthreads();
  for (int off = 128; off > 0; off >>= 1) {
    if (t < off) sd[t] += sd[t + off];
    __syncthreads();
  }
  if (t == 0) bsum[blockIdx.x] = sd[0];
}

__global__ void k_scan_bsum(int* __restrict__ bsum, int* __restrict__ rowptr_end, int nb) {
  if (threadIdx.x == 0 && blockIdx.x == 0) {
    int acc = 0;
    for (int i = 0; i < nb; ++i) { int v = bsum[i]; bsum[i] = acc; acc += v; }
    *rowptr_end = acc;
  }
}

__global__ __launch_bounds__(256) void k_scan_scatter(const int* __restrict__ cnt, const int* __restrict__ bsum,
                                                      int* __restrict__ rowptr) {
  __shared__ int sd[256];
  int base = blockIdx.x * 1024;
  int t = threadIdx.x;
  int v[4]; int s = 0;
  #pragma unroll
  for (int i = 0; i < 4; ++i) {
    int idx = base + t * 4 + i;
    v[i] = (idx < N_NODES) ? cnt[idx] : 0;
    s += v[i];
  }
  sd[t] = s; __syncthreads();
  for (int off = 1; off < 256; off <<= 1) {
    int y = (t >= off) ? sd[t - off] : 0;
    __syncthreads();
    sd[t] += y;
    __syncthreads();
  }
  int pre = bsum[blockIdx.x] + sd[t] - s;
  #pragma unroll
  for (int i = 0; i < 4; ++i) {
    int idx = base + t * 4 + i;
    if (idx < N_NODES) rowptr[idx] = pre;
    pre += v[i];
  }
}

__global__ __launch_bounds__(256) void k_fill(const int* __restrict__ src, const int* __restrict__ dst,
                                              const int* __restrict__ rowptr, int* __restrict__ cursor,
                                              int* __restrict__ esrc) {
  int i = blockIdx.x * 256 + threadIdx.x;
  if (i >= N_EDGES) return;
  int d = dst[i];
  int pos = atomicAdd(&cursor[d], 1);
  esrc[rowptr[d] + pos] = src[i];
}

// ---------------- prep: transpose W1,W2 -> bf16 hi/lo, M -> bf16 hi ----------------

__global__ __launch_bounds__(256) void k_prep(const float* __restrict__ W1, const float* __restrict__ W2,
                                              const float* __restrict__ M,
                                              unsigned short* __restrict__ W1th, unsigned short* __restrict__ W1tl,
                                              unsigned short* __restrict__ W2th, unsigned short* __restrict__ W2tl,
                                              unsigned short* __restrict__ Mth) {
  int i = blockIdx.x * 256 + threadIdx.x;   // 16384 total
  int k = i >> 7, n = i & 127;
  int t = n * DIM + k;
  float w1 = W1[i];
  unsigned short h1 = f2bf(w1);
  W1th[t] = h1;
  W1tl[t] = f2bf(w1 - bf2f(h1));
  float w2 = W2[i];
  unsigned short h2 = f2bf(w2);
  W2th[t] = h2;
  W2tl[t] = f2bf(w2 - bf2f(h2));
  Mth[t] = f2bf(M[i]);
}

// ---------------- node GEMM via MFMA, bf16 hi/lo 3-term (fp32-grade) ----------------
// out[m,n] = sum_k x[m,k] W[k,n];  A = x rows (split hi/lo in-kernel), B = Wt rows (bf16 hi/lo).
// Block: 256 thr, 128x128 tile; wave w: rows [w*32, w*32+32).

__global__ __launch_bounds__(256) void k_gemm_mfma(const float* __restrict__ x,
                                                   const unsigned short* __restrict__ Wth,
                                                   const unsigned short* __restrict__ Wtl,
                                                   float* __restrict__ out, int nrows) {
  int wave = threadIdx.x >> 6, lane = threadIdx.x & 63;
  int l15 = lane & 15, quad = lane >> 4;
  int r0 = blockIdx.x * 128 + wave * 32;
  f32x4 acc[2][8];
  #pragma unroll
  for (int mt = 0; mt < 2; ++mt)
    #pragma unroll
    for (int nt = 0; nt < 8; ++nt) acc[mt][nt] = f32x4{0.f, 0.f, 0.f, 0.f};

  union U { uint4 u; bf16x8 h; };
  #pragma unroll
  for (int ks = 0; ks < 4; ++ks) {
    int k0 = ks * 32 + quad * 8;
    bf16x8 ah[2], al[2];
    #pragma unroll
    for (int mt = 0; mt < 2; ++mt) {
      int row = r0 + mt * 16 + l15;
      row = (row < nrows) ? row : (nrows - 1);
      const float* xp = x + (size_t)row * DIM + k0;
      float xv[8];
      *(float4*)(xv)     = *(const float4*)(xp);
      *(float4*)(xv + 4) = *(const float4*)(xp + 4);
      #pragma unroll
      for (int j = 0; j < 8; ++j) {
        unsigned short h = f2bf(xv[j]);
        ah[mt][j] = (short)h;
        al[mt][j] = (short)f2bf(xv[j] - bf2f(h));
      }
    }
    #pragma unroll
    for (int nt = 0; nt < 8; ++nt) {
      U bh, bl;
      bh.u = *(const uint4*)(Wth + (nt * 16 + l15) * DIM + k0);
      bl.u = *(const uint4*)(Wtl + (nt * 16 + l15) * DIM + k0);
      #pragma unroll
      for (int mt = 0; mt < 2; ++mt) {
        acc[mt][nt] = __builtin_amdgcn_mfma_f32_16x16x32_bf16(ah[mt], bh.h, acc[mt][nt], 0, 0, 0);
        acc[mt][nt] = __builtin_amdgcn_mfma_f32_16x16x32_bf16(al[mt], bh.h, acc[mt][nt], 0, 0, 0);
        acc[mt][nt] = __builtin_amdgcn_mfma_f32_16x16x32_bf16(ah[mt], bl.h, acc[mt][nt], 0, 0, 0);
      }
    }
  }
  // C layout: col = l15, row = quad*4 + reg
  #pragma unroll
  for (int mt = 0; mt < 2; ++mt) {
    #pragma unroll
    for (int reg = 0; reg < 4; ++reg) {
      int row = r0 + mt * 16 + quad * 4 + reg;
      if (row < nrows) {
        #pragma unroll
        for (int nt = 0; nt < 8; ++nt)
          out[(size_t)row * DIM + nt * 16 + l15] = acc[mt][nt][reg];
      }
    }
  }
}

// ---------------- GCN aggregate: half-wave per node, float4, 2-edge unroll ----------------

__global__ __launch_bounds__(256) void k_agg(const float* __restrict__ h, const int* __restrict__ rowptr,
                                             const int* __restrict__ esrc, const float* __restrict__ dinv,
                                             const float* __restrict__ bias, float* __restrict__ out) {
  int node = blockIdx.x * 8 + (threadIdx.x >> 5);
  if (node >= N_NODES) return;
  int lane = threadIdx.x & 31;
  const float4* h4 = (const float4*)h;
  float di = dinv[node];
  float4 hv = h4[(size_t)node * 32 + lane];
  float ax = di * hv.x, ay = di * hv.y, az = di * hv.z, aw = di * hv.w;
  int e = rowptr[node], end = rowptr[node + 1];
  for (; e + 1 < end; e += 2) {
    int s0 = esrc[e], s1 = esrc[e + 1];
    float d0 = dinv[s0], d1 = dinv[s1];
    float4 v0 = h4[(size_t)s0 * 32 + lane];
    float4 v1 = h4[(size_t)s1 * 32 + lane];
    ax = fmaf(d0, v0.x, ax); ay = fmaf(d0, v0.y, ay); az = fmaf(d0, v0.z, az); aw = fmaf(d0, v0.w, aw);
    ax = fmaf(d1, v1.x, ax); ay = fmaf(d1, v1.y, ay); az = fmaf(d1, v1.z, az); aw = fmaf(d1, v1.w, aw);
  }
  if (e < end) {
    int s = esrc[e];
    float ds = dinv[s];
    float4 vs = h4[(size_t)s * 32 + lane];
    ax = fmaf(ds, vs.x, ax); ay = fmaf(ds, vs.y, ay); az = fmaf(ds, vs.z, az); aw = fmaf(ds, vs.w, aw);
  }
  float4 bb = ((const float4*)bias)[lane];
  float4 o;
  o.x = fmaf(di, ax, bb.x); o.y = fmaf(di, ay, bb.y);
  o.z = fmaf(di, az, bb.z); o.w = fmaf(di, aw, bb.w);
  ((float4*)out)[(size_t)node * 32 + lane] = o;
}

// ---------------- gather head (fp32) / tail (bf16) rows ----------------

__global__ __launch_bounds__(128) void k_gather(const float* __restrict__ x, const int* __restrict__ head,
                                                const int* __restrict__ tail, float* __restrict__ he,
                                                unsigned short* __restrict__ te_bf) {
  int b = blockIdx.x;
  int t = threadIdx.x;
  int lane = t & 63;
  const float2* x2 = (const float2*)x;
  if (t < 64) {
    ((float2*)he)[b * 64 + lane] = x2[(size_t)head[b] * 64 + lane];
  } else {
    float2 v = x2[(size_t)tail[b] * 64 + lane];
    ushort2 o; o.x = f2bf(v.x); o.y = f2bf(v.y);
    ((ushort2*)te_bf)[b * 64 + lane] = o;
  }
}

// ---------------- fused decoder precompute: T_r = Rel_r @ M (LDS), Q_r = T_r @ Rel_r^T ----------------
// grid (86, 2): block handles 64 d-rows of one relation. All MFMA bf16.

#define TPAD 136  // 128+8 bf16 -> row stride 272 B (17*16B): 16B-aligned, 2-way bank alias (free)

__global__ __launch_bounds__(256) void k_decoder_TQ(const float* __restrict__ Rel,
                                                    const unsigned short* __restrict__ Mth,
                                                    unsigned short* __restrict__ Qbf) {
  __shared__ __align__(16) unsigned short Ts[64 * TPAD];
  int r = blockIdx.x;
  int dblk = blockIdx.y;
  const float* Rr = Rel + (size_t)r * DIM * DIM;
  unsigned short* Qr = Qbf + (size_t)r * DIM * DIM;
  int wave = threadIdx.x >> 6, lane = threadIdx.x & 63;
  int l15 = lane & 15, quad = lane >> 4;
  int dw = dblk * 64 + wave * 16;  // this wave's 16 d-rows

  union U { uint4 u; bf16x8 h; };
  // step 1: T[d, f] = sum_e Rel[d,e] M[e,f];  A = Rel rows, B = Mt rows
  f32x4 acc[8];
  #pragma unroll
  for (int nt = 0; nt < 8; ++nt) acc[nt] = f32x4{0.f, 0.f, 0.f, 0.f};
  #pragma unroll
  for (int ks = 0; ks < 4; ++ks) {
    int k0 = ks * 32 + quad * 8;
    const float* ap = Rr + (size_t)(dw + l15) * DIM + k0;
    float av[8];
    *(float4*)(av)     = *(const float4*)(ap);
    *(float4*)(av + 4) = *(const float4*)(ap + 4);
    bf16x8 a;
    #pragma unroll
    for (int j = 0; j < 8; ++j) a[j] = (short)f2bf(av[j]);
    #pragma unroll
    for (int nt = 0; nt < 8; ++nt) {
      U b; b.u = *(const uint4*)(Mth + (nt * 16 + l15) * DIM + k0);
      acc[nt] = __builtin_amdgcn_mfma_f32_16x16x32_bf16(a, b.h, acc[nt], 0, 0, 0);
    }
  }
  #pragma unroll
  for (int nt = 0; nt < 8; ++nt)
    #pragma unroll
    for (int reg = 0; reg < 4; ++reg)
      Ts[(wave * 16 + quad * 4 + reg) * TPAD + nt * 16 + l15] = f2bf(acc[nt][reg]);
  __syncthreads();

  // step 2: Q[d, e] = sum_f T[d,f] Rel[e,f];  A = T rows (LDS), B = Rel rows
  f32x4 qacc[8];
  #pragma unroll
  for (int nt = 0; nt < 8; ++nt) qacc[nt] = f32x4{0.f, 0.f, 0.f, 0.f};
  #pragma unroll
  for (int ks = 0; ks < 4; ++ks) {
    int k0 = ks * 32 + quad * 8;
    U a; a.u = *(const uint4*)(Ts + (wave * 16 + l15) * TPAD + k0);
    #pragma unroll
    for (int nt = 0; nt < 8; ++nt) {
      const float* bp = Rr + (size_t)(nt * 16 + l15) * DIM + k0;
      float bv[8];
      *(float4*)(bv)     = *(const float4*)(bp);
      *(float4*)(bv + 4) = *(const float4*)(bp + 4);
      bf16x8 b;
      #pragma unroll
      for (int j = 0; j < 8; ++j) b[j] = (short)f2bf(bv[j]);
      qacc[nt] = __builtin_amdgcn_mfma_f32_16x16x32_bf16(a.h, b, qacc[nt], 0, 0, 0);
    }
  }
  #pragma unroll
  for (int nt = 0; nt < 8; ++nt)
    #pragma unroll
    for (int reg = 0; reg < 4; ++reg)
      Qr[(size_t)(dw + quad * 4 + reg) * DIM + nt * 16 + l15] = f2bf(qacc[nt][reg]);
}

// ---------------- predict via MFMA (unchanged from round 4) ----------------

#define QPAD 136

__global__ __launch_bounds__(256) void k_predict_mfma(const float* __restrict__ he,
                                                      const unsigned short* __restrict__ te_bf,
                                                      const unsigned short* __restrict__ Qbf,
                                                      float* __restrict__ out) {
  __shared__ __align__(16) unsigned short Qs[DIM * QPAD];
  int r = blockIdx.y;
  const unsigned short* Qr = Qbf + (size_t)r * DIM * DIM;
  for (int i = threadIdx.x; i < DIM * DIM / 8; i += 256) {
    int d = i >> 4, c = (i & 15) * 8;
    uint4 v = ((const uint4*)Qr)[i];
    *(uint4*)(&Qs[d * QPAD + c]) = v;
  }
  __syncthreads();
  int wave = threadIdx.x >> 6, lane = threadIdx.x & 63;
  int l15 = lane & 15, quad = lane >> 4;
  int bbase = blockIdx.x * 128 + wave * 32;

  f32x4 acc[2][8];
  #pragma unroll
  for (int m = 0; m < 2; ++m)
    #pragma unroll
    for (int n = 0; n < 8; ++n) acc[m][n] = f32x4{0.f, 0.f, 0.f, 0.f};

  union U { uint4 u; bf16x8 h; };
  #pragma unroll
  for (int ks = 0; ks < 4; ++ks) {
    int eoff = ks * 32 + quad * 8;
    U a0, a1;
    a0.u = *(const uint4*)(te_bf + (size_t)(bbase + l15) * DIM + eoff);
    a1.u = *(const uint4*)(te_bf + (size_t)(bbase + 16 + l15) * DIM + eoff);
    #pragma unroll
    for (int nt = 0; nt < 8; ++nt) {
      U b; b.u = *(const uint4*)(&Qs[(nt * 16 + l15) * QPAD + eoff]);
      acc[0][nt] = __builtin_amdgcn_mfma_f32_16x16x32_bf16(a0.h, b.h, acc[0][nt], 0, 0, 0);
      acc[1][nt] = __builtin_amdgcn_mfma_f32_16x16x32_bf16(a1.h, b.h, acc[1][nt], 0, 0, 0);
    }
  }

  #pragma unroll
  for (int m = 0; m < 2; ++m) {
    #pragma unroll
    for (int reg = 0; reg < 4; ++reg) {
      int b = bbase + m * 16 + quad * 4 + reg;
      float s = 0.f;
      #pragma unroll
      for (int nt = 0; nt < 8; ++nt)
        s += he[(size_t)b * DIM + nt * 16 + l15] * acc[m][nt][reg];
      #pragma unroll
      for (int off = 1; off < 16; off <<= 1) s += __shfl_xor(s, off, 64);
      if (l15 == 0) out[(size_t)b * N_REL + r] = s;
    }
  }
}

// ---------------- launch ----------------

extern "C" void kernel_launch(void* const* d_in, const int* in_sizes, int n_in,
                              void* d_out, int out_size, void* d_ws, size_t ws_size,
                              hipStream_t stream) {
  (void)in_sizes; (void)n_in; (void)out_size; (void)ws_size;
  const float* init_emb = (const float*)d_in[0];
  const float* W1  = (const float*)d_in[1];
  const float* b1  = (const float*)d_in[2];
  const float* W2  = (const float*)d_in[3];
  const float* b2  = (const float*)d_in[4];
  const float* Rel = (const float*)d_in[5];
  const float* M   = (const float*)d_in[6];
  const int* head  = (const int*)d_in[7];
  const int* tail  = (const int*)d_in[8];
  const int* src   = (const int*)d_in[9];
  const int* dst   = src + N_EDGES;
  float* out = (float*)d_out;

  char* p = (char*)d_ws;
  auto alloc = [&](size_t bytes) { char* q = p; p += (bytes + 511) & ~(size_t)511; return q; };
  int*   cnt    = (int*)alloc((size_t)N_NODES * 4);
  int*   cursor = (int*)alloc((size_t)N_NODES * 4);
  int*   rowptr = (int*)alloc((size_t)(N_NODES + 1) * 4);
  int*   bsum   = (int*)alloc(64 * 4);
  int*   esrc   = (int*)alloc((size_t)N_EDGES * 4);
  float* dinv   = (float*)alloc((size_t)N_NODES * 4);
  float* bufA   = (float*)alloc((size_t)N_NODES * DIM * 4);
  float* bufB   = (float*)alloc((size_t)N_NODES * DIM * 4);
  float* he     = (float*)alloc((size_t)BATCH * DIM * 4);
  unsigned short* te_bf = (unsigned short*)alloc((size_t)BATCH * DIM * 2);
  unsigned short* Qbf   = (unsigned short*)alloc((size_t)N_REL * DIM * DIM * 2);
  unsigned short* W1th  = (unsigned short*)alloc((size_t)DIM * DIM * 2);
  unsigned short* W1tl  = (unsigned short*)alloc((size_t)DIM * DIM * 2);
  unsigned short* W2th  = (unsigned short*)alloc((size_t)DIM * DIM * 2);
  unsigned short* W2tl  = (unsigned short*)alloc((size_t)DIM * DIM * 2);
  unsigned short* Mth   = (unsigned short*)alloc((size_t)DIM * DIM * 2);

  hipMemsetAsync(cnt, 0, (size_t)N_NODES * 4, stream);
  hipMemsetAsync(cursor, 0, (size_t)N_NODES * 4, stream);

  k_prep<<<64, 256, 0, stream>>>(W1, W2, M, W1th, W1tl, W2th, W2tl, Mth);

  k_count<<<(N_EDGES + 255) / 256, 256, 0, stream>>>(dst, cnt);
  k_dinv<<<(N_NODES + 255) / 256, 256, 0, stream>>>(cnt, dinv);
  int nb = (N_NODES + 1023) / 1024;  // 49
  k_scan_reduce<<<nb, 256, 0, stream>>>(cnt, bsum);
  k_scan_bsum<<<1, 64, 0, stream>>>(bsum, rowptr + N_NODES, nb);
  k_scan_scatter<<<nb, 256, 0, stream>>>(cnt, bsum, rowptr);
  k_fill<<<(N_EDGES + 255) / 256, 256, 0, stream>>>(src, dst, rowptr, cursor, esrc);

  // layer 1
  k_gemm_mfma<<<(N_NODES + 127) / 128, 256, 0, stream>>>(init_emb, W1th, W1tl, bufA, N_NODES);
  k_agg<<<(N_NODES + 7) / 8, 256, 0, stream>>>(bufA, rowptr, esrc, dinv, b1, bufB);
  // layer 2
  k_gemm_mfma<<<(N_NODES + 127) / 128, 256, 0, stream>>>(bufB, W2th, W2tl, bufA, N_NODES);
  k_agg<<<(N_NODES + 7) / 8, 256, 0, stream>>>(bufA, rowptr, esrc, dinv, b2, bufB);

  // decoder
  k_gather<<<BATCH, 128, 0, stream>>>(bufB, head, tail, he, te_bf);
  k_decoder_TQ<<<dim3(N_REL, 2), 256, 0, stream>>>(Rel, Mth, Qbf);
  k_predict_mfma<<<dim3(BATCH / 128, N_REL), 256, 0, stream>>>(he, te_bf, Qbf, out);
}

// Round 6
// 335.252 us; speedup vs baseline: 4.0783x; 1.1469x over previous
//
#include <hip/hip_runtime.h>

#define N_NODES 50000
#define N_EDGES 800000
#define DIM 128
#define N_REL 86
#define BATCH 2048

using bf16x8 = __attribute__((ext_vector_type(8))) short;
using f32x4  = __attribute__((ext_vector_type(4))) float;

// float -> bf16 round-to-nearest-even (finite inputs)
static __device__ __forceinline__ unsigned short f2bf(float f) {
  union { float f; unsigned int i; } v; v.f = f;
  unsigned int x = v.i;
  unsigned int r = x + 0x7FFFu + ((x >> 16) & 1u);
  return (unsigned short)(r >> 16);
}
static __device__ __forceinline__ float bf2f(unsigned short u) {
  union { unsigned int i; float f; } v;
  v.i = ((unsigned int)u) << 16;
  return v.f;
}

// ---------------- degree / CSR build ----------------

__global__ __launch_bounds__(256) void k_count(const int* __restrict__ dst, int* __restrict__ cnt) {
  int i = blockIdx.x * 256 + threadIdx.x;
  if (i < N_EDGES) atomicAdd(&cnt[dst[i]], 1);
}

__global__ __launch_bounds__(256) void k_dinv(const int* __restrict__ cnt, float* __restrict__ dinv) {
  int i = blockIdx.x * 256 + threadIdx.x;
  if (i < N_NODES) dinv[i] = rsqrtf((float)(cnt[i] + 1));
}

__global__ __launch_bounds__(256) void k_scan_reduce(const int* __restrict__ cnt, int* __restrict__ bsum) {
  __shared__ int sd[256];
  int base = blockIdx.x * 1024;
  int t = threadIdx.x;
  int s = 0;
  #pragma unroll
  for (int i = 0; i < 4; ++i) {
    int idx = base + t * 4 + i;
    if (idx < N_NODES) s += cnt[idx];
  }
  sd[t] = s; __syncthreads();
  for (int off = 128; off > 0; off >>= 1) {
    if (t < off) sd[t] += sd[t + off];
    __syncthreads();
  }
  if (t == 0) bsum[blockIdx.x] = sd[0];
}

__global__ void k_scan_bsum(int* __restrict__ bsum, int* __restrict__ rowptr_end, int nb) {
  if (threadIdx.x == 0 && blockIdx.x == 0) {
    int acc = 0;
    for (int i = 0; i < nb; ++i) { int v = bsum[i]; bsum[i] = acc; acc += v; }
    *rowptr_end = acc;
  }
}

__global__ __launch_bounds__(256) void k_scan_scatter(const int* __restrict__ cnt, const int* __restrict__ bsum,
                                                      int* __restrict__ rowptr) {
  __shared__ int sd[256];
  int base = blockIdx.x * 1024;
  int t = threadIdx.x;
  int v[4]; int s = 0;
  #pragma unroll
  for (int i = 0; i < 4; ++i) {
    int idx = base + t * 4 + i;
    v[i] = (idx < N_NODES) ? cnt[idx] : 0;
    s += v[i];
  }
  sd[t] = s; __syncthreads();
  for (int off = 1; off < 256; off <<= 1) {
    int y = (t >= off) ? sd[t - off] : 0;
    __syncthreads();
    sd[t] += y;
    __syncthreads();
  }
  int pre = bsum[blockIdx.x] + sd[t] - s;
  #pragma unroll
  for (int i = 0; i < 4; ++i) {
    int idx = base + t * 4 + i;
    if (idx < N_NODES) rowptr[idx] = pre;
    pre += v[i];
  }
}

__global__ __launch_bounds__(256) void k_fill(const int* __restrict__ src, const int* __restrict__ dst,
                                              const int* __restrict__ rowptr, int* __restrict__ cursor,
                                              int* __restrict__ esrc) {
  int i = blockIdx.x * 256 + threadIdx.x;
  if (i >= N_EDGES) return;
  int d = dst[i];
  int pos = atomicAdd(&cursor[d], 1);
  esrc[rowptr[d] + pos] = src[i];
}

// ---------------- prep: transpose W1,W2 -> bf16 hi/lo, M -> bf16 hi ----------------

__global__ __launch_bounds__(256) void k_prep(const float* __restrict__ W1, const float* __restrict__ W2,
                                              const float* __restrict__ M,
                                              unsigned short* __restrict__ W1th, unsigned short* __restrict__ W1tl,
                                              unsigned short* __restrict__ W2th, unsigned short* __restrict__ W2tl,
                                              unsigned short* __restrict__ Mth) {
  int i = blockIdx.x * 256 + threadIdx.x;   // 16384 total
  int k = i >> 7, n = i & 127;
  int t = n * DIM + k;
  float w1 = W1[i];
  unsigned short h1 = f2bf(w1);
  W1th[t] = h1;
  W1tl[t] = f2bf(w1 - bf2f(h1));
  float w2 = W2[i];
  unsigned short h2 = f2bf(w2);
  W2th[t] = h2;
  W2tl[t] = f2bf(w2 - bf2f(h2));
  Mth[t] = f2bf(M[i]);
}

// ---------------- node GEMM via MFMA, bf16 hi/lo 3-term; OUTPUT bf16 ----------------
// out[m,n] = sum_k x[m,k] W[k,n];  A = x rows (split hi/lo), B = Wt rows.
// h is only consumed by the aggregation, which tolerates bf16 (one rounding).

__global__ __launch_bounds__(256) void k_gemm_mfma(const float* __restrict__ x,
                                                   const unsigned short* __restrict__ Wth,
                                                   const unsigned short* __restrict__ Wtl,
                                                   unsigned short* __restrict__ out, int nrows) {
  int wave = threadIdx.x >> 6, lane = threadIdx.x & 63;
  int l15 = lane & 15, quad = lane >> 4;
  int r0 = blockIdx.x * 128 + wave * 32;
  f32x4 acc[2][8];
  #pragma unroll
  for (int mt = 0; mt < 2; ++mt)
    #pragma unroll
    for (int nt = 0; nt < 8; ++nt) acc[mt][nt] = f32x4{0.f, 0.f, 0.f, 0.f};

  union U { uint4 u; bf16x8 h; };
  #pragma unroll
  for (int ks = 0; ks < 4; ++ks) {
    int k0 = ks * 32 + quad * 8;
    bf16x8 ah[2], al[2];
    #pragma unroll
    for (int mt = 0; mt < 2; ++mt) {
      int row = r0 + mt * 16 + l15;
      row = (row < nrows) ? row : (nrows - 1);
      const float* xp = x + (size_t)row * DIM + k0;
      float xv[8];
      *(float4*)(xv)     = *(const float4*)(xp);
      *(float4*)(xv + 4) = *(const float4*)(xp + 4);
      #pragma unroll
      for (int j = 0; j < 8; ++j) {
        unsigned short h = f2bf(xv[j]);
        ah[mt][j] = (short)h;
        al[mt][j] = (short)f2bf(xv[j] - bf2f(h));
      }
    }
    #pragma unroll
    for (int nt = 0; nt < 8; ++nt) {
      U bh, bl;
      bh.u = *(const uint4*)(Wth + (nt * 16 + l15) * DIM + k0);
      bl.u = *(const uint4*)(Wtl + (nt * 16 + l15) * DIM + k0);
      #pragma unroll
      for (int mt = 0; mt < 2; ++mt) {
        acc[mt][nt] = __builtin_amdgcn_mfma_f32_16x16x32_bf16(ah[mt], bh.h, acc[mt][nt], 0, 0, 0);
        acc[mt][nt] = __builtin_amdgcn_mfma_f32_16x16x32_bf16(al[mt], bh.h, acc[mt][nt], 0, 0, 0);
        acc[mt][nt] = __builtin_amdgcn_mfma_f32_16x16x32_bf16(ah[mt], bl.h, acc[mt][nt], 0, 0, 0);
      }
    }
  }
  // C layout: col = l15, row = quad*4 + reg
  #pragma unroll
  for (int mt = 0; mt < 2; ++mt) {
    #pragma unroll
    for (int reg = 0; reg < 4; ++reg) {
      int row = r0 + mt * 16 + quad * 4 + reg;
      if (row < nrows) {
        #pragma unroll
        for (int nt = 0; nt < 8; ++nt)
          out[(size_t)row * DIM + nt * 16 + l15] = f2bf(acc[mt][nt][reg]);
      }
    }
  }
}

// ---------------- GCN aggregate: half-wave per node, bf16 h rows, 4-edge unroll ----------------
// out[d] = dinv[d]*(sum_in dinv[s]h[s] + dinv[d]h[d]) + b  (fp32 accumulate, fp32 out)

__global__ __launch_bounds__(256) void k_agg(const unsigned short* __restrict__ h, const int* __restrict__ rowptr,
                                             const int* __restrict__ esrc, const float* __restrict__ dinv,
                                             const float* __restrict__ bias, float* __restrict__ out) {
  int node = blockIdx.x * 8 + (threadIdx.x >> 5);
  if (node >= N_NODES) return;
  int lane = threadIdx.x & 31;
  const ushort4* h4 = (const ushort4*)h;   // 4 bf16 per lane, row = 256 B
  float di = dinv[node];
  ushort4 hv = h4[(size_t)node * 32 + lane];
  float ax = di * bf2f(hv.x), ay = di * bf2f(hv.y), az = di * bf2f(hv.z), aw = di * bf2f(hv.w);
  int e = rowptr[node], end = rowptr[node + 1];
  for (; e + 3 < end; e += 4) {
    int s0 = esrc[e], s1 = esrc[e + 1], s2 = esrc[e + 2], s3 = esrc[e + 3];
    float d0 = dinv[s0], d1 = dinv[s1], d2 = dinv[s2], d3 = dinv[s3];
    ushort4 v0 = h4[(size_t)s0 * 32 + lane];
    ushort4 v1 = h4[(size_t)s1 * 32 + lane];
    ushort4 v2 = h4[(size_t)s2 * 32 + lane];
    ushort4 v3 = h4[(size_t)s3 * 32 + lane];
    ax = fmaf(d0, bf2f(v0.x), ax); ay = fmaf(d0, bf2f(v0.y), ay); az = fmaf(d0, bf2f(v0.z), az); aw = fmaf(d0, bf2f(v0.w), aw);
    ax = fmaf(d1, bf2f(v1.x), ax); ay = fmaf(d1, bf2f(v1.y), ay); az = fmaf(d1, bf2f(v1.z), az); aw = fmaf(d1, bf2f(v1.w), aw);
    ax = fmaf(d2, bf2f(v2.x), ax); ay = fmaf(d2, bf2f(v2.y), ay); az = fmaf(d2, bf2f(v2.z), az); aw = fmaf(d2, bf2f(v2.w), aw);
    ax = fmaf(d3, bf2f(v3.x), ax); ay = fmaf(d3, bf2f(v3.y), ay); az = fmaf(d3, bf2f(v3.z), az); aw = fmaf(d3, bf2f(v3.w), aw);
  }
  for (; e < end; ++e) {
    int s = esrc[e];
    float ds = dinv[s];
    ushort4 vs = h4[(size_t)s * 32 + lane];
    ax = fmaf(ds, bf2f(vs.x), ax); ay = fmaf(ds, bf2f(vs.y), ay);
    az = fmaf(ds, bf2f(vs.z), az); aw = fmaf(ds, bf2f(vs.w), aw);
  }
  float4 bb = ((const float4*)bias)[lane];
  float4 o;
  o.x = fmaf(di, ax, bb.x); o.y = fmaf(di, ay, bb.y);
  o.z = fmaf(di, az, bb.z); o.w = fmaf(di, aw, bb.w);
  ((float4*)out)[(size_t)node * 32 + lane] = o;
}

// ---------------- gather head (fp32) / tail (bf16) rows ----------------

__global__ __launch_bounds__(128) void k_gather(const float* __restrict__ x, const int* __restrict__ head,
                                                const int* __restrict__ tail, float* __restrict__ he,
                                                unsigned short* __restrict__ te_bf) {
  int b = blockIdx.x;
  int t = threadIdx.x;
  int lane = t & 63;
  const float2* x2 = (const float2*)x;
  if (t < 64) {
    ((float2*)he)[b * 64 + lane] = x2[(size_t)head[b] * 64 + lane];
  } else {
    float2 v = x2[(size_t)tail[b] * 64 + lane];
    ushort2 o; o.x = f2bf(v.x); o.y = f2bf(v.y);
    ((ushort2*)te_bf)[b * 64 + lane] = o;
  }
}

// ---------------- fused decoder precompute: T_r = Rel_r @ M (LDS), Q_r = T_r @ Rel_r^T ----------------

#define TPAD 136

__global__ __launch_bounds__(256) void k_decoder_TQ(const float* __restrict__ Rel,
                                                    const unsigned short* __restrict__ Mth,
                                                    unsigned short* __restrict__ Qbf) {
  __shared__ __align__(16) unsigned short Ts[64 * TPAD];
  int r = blockIdx.x;
  int dblk = blockIdx.y;
  const float* Rr = Rel + (size_t)r * DIM * DIM;
  unsigned short* Qr = Qbf + (size_t)r * DIM * DIM;
  int wave = threadIdx.x >> 6, lane = threadIdx.x & 63;
  int l15 = lane & 15, quad = lane >> 4;
  int dw = dblk * 64 + wave * 16;

  union U { uint4 u; bf16x8 h; };
  // step 1: T[d, f] = sum_e Rel[d,e] M[e,f]
  f32x4 acc[8];
  #pragma unroll
  for (int nt = 0; nt < 8; ++nt) acc[nt] = f32x4{0.f, 0.f, 0.f, 0.f};
  #pragma unroll
  for (int ks = 0; ks < 4; ++ks) {
    int k0 = ks * 32 + quad * 8;
    const float* ap = Rr + (size_t)(dw + l15) * DIM + k0;
    float av[8];
    *(float4*)(av)     = *(const float4*)(ap);
    *(float4*)(av + 4) = *(const float4*)(ap + 4);
    bf16x8 a;
    #pragma unroll
    for (int j = 0; j < 8; ++j) a[j] = (short)f2bf(av[j]);
    #pragma unroll
    for (int nt = 0; nt < 8; ++nt) {
      U b; b.u = *(const uint4*)(Mth + (nt * 16 + l15) * DIM + k0);
      acc[nt] = __builtin_amdgcn_mfma_f32_16x16x32_bf16(a, b.h, acc[nt], 0, 0, 0);
    }
  }
  #pragma unroll
  for (int nt = 0; nt < 8; ++nt)
    #pragma unroll
    for (int reg = 0; reg < 4; ++reg)
      Ts[(wave * 16 + quad * 4 + reg) * TPAD + nt * 16 + l15] = f2bf(acc[nt][reg]);
  __syncthreads();

  // step 2: Q[d, e] = sum_f T[d,f] Rel[e,f]
  f32x4 qacc[8];
  #pragma unroll
  for (int nt = 0; nt < 8; ++nt) qacc[nt] = f32x4{0.f, 0.f, 0.f, 0.f};
  #pragma unroll
  for (int ks = 0; ks < 4; ++ks) {
    int k0 = ks * 32 + quad * 8;
    U a; a.u = *(const uint4*)(Ts + (wave * 16 + l15) * TPAD + k0);
    #pragma unroll
    for (int nt = 0; nt < 8; ++nt) {
      const float* bp = Rr + (size_t)(nt * 16 + l15) * DIM + k0;
      float bv[8];
      *(float4*)(bv)     = *(const float4*)(bp);
      *(float4*)(bv + 4) = *(const float4*)(bp + 4);
      bf16x8 b;
      #pragma unroll
      for (int j = 0; j < 8; ++j) b[j] = (short)f2bf(bv[j]);
      qacc[nt] = __builtin_amdgcn_mfma_f32_16x16x32_bf16(a.h, b, qacc[nt], 0, 0, 0);
    }
  }
  #pragma unroll
  for (int nt = 0; nt < 8; ++nt)
    #pragma unroll
    for (int reg = 0; reg < 4; ++reg)
      Qr[(size_t)(dw + quad * 4 + reg) * DIM + nt * 16 + l15] = f2bf(qacc[nt][reg]);
}

// ---------------- predict via MFMA ----------------

#define QPAD 136

__global__ __launch_bounds__(256) void k_predict_mfma(const float* __restrict__ he,
                                                      const unsigned short* __restrict__ te_bf,
                                                      const unsigned short* __restrict__ Qbf,
                                                      float* __restrict__ out) {
  __shared__ __align__(16) unsigned short Qs[DIM * QPAD];
  int r = blockIdx.y;
  const unsigned short* Qr = Qbf + (size_t)r * DIM * DIM;
  for (int i = threadIdx.x; i < DIM * DIM / 8; i += 256) {
    int d = i >> 4, c = (i & 15) * 8;
    uint4 v = ((const uint4*)Qr)[i];
    *(uint4*)(&Qs[d * QPAD + c]) = v;
  }
  __syncthreads();
  int wave = threadIdx.x >> 6, lane = threadIdx.x & 63;
  int l15 = lane & 15, quad = lane >> 4;
  int bbase = blockIdx.x * 128 + wave * 32;

  f32x4 acc[2][8];
  #pragma unroll
  for (int m = 0; m < 2; ++m)
    #pragma unroll
    for (int n = 0; n < 8; ++n) acc[m][n] = f32x4{0.f, 0.f, 0.f, 0.f};

  union U { uint4 u; bf16x8 h; };
  #pragma unroll
  for (int ks = 0; ks < 4; ++ks) {
    int eoff = ks * 32 + quad * 8;
    U a0, a1;
    a0.u = *(const uint4*)(te_bf + (size_t)(bbase + l15) * DIM + eoff);
    a1.u = *(const uint4*)(te_bf + (size_t)(bbase + 16 + l15) * DIM + eoff);
    #pragma unroll
    for (int nt = 0; nt < 8; ++nt) {
      U b; b.u = *(const uint4*)(&Qs[(nt * 16 + l15) * QPAD + eoff]);
      acc[0][nt] = __builtin_amdgcn_mfma_f32_16x16x32_bf16(a0.h, b.h, acc[0][nt], 0, 0, 0);
      acc[1][nt] = __builtin_amdgcn_mfma_f32_16x16x32_bf16(a1.h, b.h, acc[1][nt], 0, 0, 0);
    }
  }

  #pragma unroll
  for (int m = 0; m < 2; ++m) {
    #pragma unroll
    for (int reg = 0; reg < 4; ++reg) {
      int b = bbase + m * 16 + quad * 4 + reg;
      float s = 0.f;
      #pragma unroll
      for (int nt = 0; nt < 8; ++nt)
        s += he[(size_t)b * DIM + nt * 16 + l15] * acc[m][nt][reg];
      #pragma unroll
      for (int off = 1; off < 16; off <<= 1) s += __shfl_xor(s, off, 64);
      if (l15 == 0) out[(size_t)b * N_REL + r] = s;
    }
  }
}

// ---------------- launch ----------------

extern "C" void kernel_launch(void* const* d_in, const int* in_sizes, int n_in,
                              void* d_out, int out_size, void* d_ws, size_t ws_size,
                              hipStream_t stream) {
  (void)in_sizes; (void)n_in; (void)out_size; (void)ws_size;
  const float* init_emb = (const float*)d_in[0];
  const float* W1  = (const float*)d_in[1];
  const float* b1  = (const float*)d_in[2];
  const float* W2  = (const float*)d_in[3];
  const float* b2  = (const float*)d_in[4];
  const float* Rel = (const float*)d_in[5];
  const float* M   = (const float*)d_in[6];
  const int* head  = (const int*)d_in[7];
  const int* tail  = (const int*)d_in[8];
  const int* src   = (const int*)d_in[9];
  const int* dst   = src + N_EDGES;
  float* out = (float*)d_out;

  char* p = (char*)d_ws;
  auto alloc = [&](size_t bytes) { char* q = p; p += (bytes + 511) & ~(size_t)511; return q; };
  int*   cnt    = (int*)alloc((size_t)N_NODES * 4);
  int*   cursor = (int*)alloc((size_t)N_NODES * 4);
  int*   rowptr = (int*)alloc((size_t)(N_NODES + 1) * 4);
  int*   bsum   = (int*)alloc(64 * 4);
  int*   esrc   = (int*)alloc((size_t)N_EDGES * 4);
  float* dinv   = (float*)alloc((size_t)N_NODES * 4);
  unsigned short* hbuf = (unsigned short*)alloc((size_t)N_NODES * DIM * 2);  // GEMM out (bf16)
  float* bufB   = (float*)alloc((size_t)N_NODES * DIM * 4);                  // agg out (fp32)
  float* he     = (float*)alloc((size_t)BATCH * DIM * 4);
  unsigned short* te_bf = (unsigned short*)alloc((size_t)BATCH * DIM * 2);
  unsigned short* Qbf   = (unsigned short*)alloc((size_t)N_REL * DIM * DIM * 2);
  unsigned short* W1th  = (unsigned short*)alloc((size_t)DIM * DIM * 2);
  unsigned short* W1tl  = (unsigned short*)alloc((size_t)DIM * DIM * 2);
  unsigned short* W2th  = (unsigned short*)alloc((size_t)DIM * DIM * 2);
  unsigned short* W2tl  = (unsigned short*)alloc((size_t)DIM * DIM * 2);
  unsigned short* Mth   = (unsigned short*)alloc((size_t)DIM * DIM * 2);

  hipMemsetAsync(cnt, 0, (size_t)N_NODES * 4, stream);
  hipMemsetAsync(cursor, 0, (size_t)N_NODES * 4, stream);

  k_prep<<<64, 256, 0, stream>>>(W1, W2, M, W1th, W1tl, W2th, W2tl, Mth);

  k_count<<<(N_EDGES + 255) / 256, 256, 0, stream>>>(dst, cnt);
  k_dinv<<<(N_NODES + 255) / 256, 256, 0, stream>>>(cnt, dinv);
  int nb = (N_NODES + 1023) / 1024;  // 49
  k_scan_reduce<<<nb, 256, 0, stream>>>(cnt, bsum);
  k_scan_bsum<<<1, 64, 0, stream>>>(bsum, rowptr + N_NODES, nb);
  k_scan_scatter<<<nb, 256, 0, stream>>>(cnt, bsum, rowptr);
  k_fill<<<(N_EDGES + 255) / 256, 256, 0, stream>>>(src, dst, rowptr, cursor, esrc);

  // layer 1
  k_gemm_mfma<<<(N_NODES + 127) / 128, 256, 0, stream>>>(init_emb, W1th, W1tl, hbuf, N_NODES);
  k_agg<<<(N_NODES + 7) / 8, 256, 0, stream>>>(hbuf, rowptr, esrc, dinv, b1, bufB);
  // layer 2
  k_gemm_mfma<<<(N_NODES + 127) / 128, 256, 0, stream>>>(bufB, W2th, W2tl, hbuf, N_NODES);
  k_agg<<<(N_NODES + 7) / 8, 256, 0, stream>>>(hbuf, rowptr, esrc, dinv, b2, bufB);

  // decoder
  k_gather<<<BATCH, 128, 0, stream>>>(bufB, head, tail, he, te_bf);
  k_decoder_TQ<<<dim3(N_REL, 2), 256, 0, stream>>>(Rel, Mth, Qbf);
  k_predict_mfma<<<dim3(BATCH / 128, N_REL), 256, 0, stream>>>(he, te_bf, Qbf, out);
}

// Round 7
// 318.552 us; speedup vs baseline: 4.2921x; 1.0524x over previous
//
#include <hip/hip_runtime.h>

#define N_NODES 50000
#define N_EDGES 800000
#define DIM 128
#define N_REL 86
#define BATCH 2048

using bf16x8 = __attribute__((ext_vector_type(8))) short;
using f32x4  = __attribute__((ext_vector_type(4))) float;

// float -> bf16 round-to-nearest-even (finite inputs)
static __device__ __forceinline__ unsigned short f2bf(float f) {
  union { float f; unsigned int i; } v; v.f = f;
  unsigned int x = v.i;
  unsigned int r = x + 0x7FFFu + ((x >> 16) & 1u);
  return (unsigned short)(r >> 16);
}
static __device__ __forceinline__ float bf2f(unsigned short u) {
  union { unsigned int i; float f; } v;
  v.i = ((unsigned int)u) << 16;
  return v.f;
}

// ---------------- kernel 0: zero cnt + weight prep ----------------

__global__ __launch_bounds__(256) void k_prep_zero(const float* __restrict__ W1, const float* __restrict__ W2,
                                                   const float* __restrict__ M,
                                                   unsigned short* __restrict__ W1th, unsigned short* __restrict__ W1tl,
                                                   unsigned short* __restrict__ W2th, unsigned short* __restrict__ W2tl,
                                                   unsigned short* __restrict__ Mth,
                                                   int* __restrict__ cnt) {
  int g = blockIdx.x * 256 + threadIdx.x;          // grid 256 blocks -> 65536 threads
  if (g < N_NODES) cnt[g] = 0;
  if (g < DIM * DIM) {
    int k = g >> 7, n = g & 127;
    int t = n * DIM + k;
    float w1 = W1[g];
    unsigned short h1 = f2bf(w1);
    W1th[t] = h1;
    W1tl[t] = f2bf(w1 - bf2f(h1));
    float w2 = W2[g];
    unsigned short h2 = f2bf(w2);
    W2th[t] = h2;
    W2tl[t] = f2bf(w2 - bf2f(h2));
    Mth[t] = f2bf(M[g]);
  }
}

// ---------------- mega kernel 1: gemm1 (fp32 x -> bf16 h)  ||  decoder TQ  ||  edge count ----------------

#define G_GEMM 391            // ceil(50000/128)
#define G_TQ   172            // 86 relations x 2 d-blocks
#define G_CNT  782            // ceil(800000/1024), 4 edges/thread
#define TPAD 136              // 128+8 bf16: 272 B row stride, 16B-aligned, 2-way bank alias (free)

__global__ __launch_bounds__(256) void k_mega1(const float* __restrict__ x,
                                               const unsigned short* __restrict__ W1th,
                                               const unsigned short* __restrict__ W1tl,
                                               unsigned short* __restrict__ hout,
                                               const float* __restrict__ Rel,
                                               const unsigned short* __restrict__ Mth,
                                               unsigned short* __restrict__ Qbf,
                                               const int* __restrict__ dst,
                                               int* __restrict__ cnt) {
  __shared__ __align__(16) unsigned short Ts[64 * TPAD];
  int bid = blockIdx.x;
  int wave = threadIdx.x >> 6, lane = threadIdx.x & 63;
  int l15 = lane & 15, quad = lane >> 4;
  union U { uint4 u; bf16x8 h; };

  if (bid < G_GEMM) {
    // ---- node GEMM layer 1: hout[m,n] = sum_k x[m,k] W1[k,n], hi/lo 3-term ----
    int r0 = bid * 128 + wave * 32;
    f32x4 acc[2][8];
    #pragma unroll
    for (int mt = 0; mt < 2; ++mt)
      #pragma unroll
      for (int nt = 0; nt < 8; ++nt) acc[mt][nt] = f32x4{0.f, 0.f, 0.f, 0.f};
    #pragma unroll
    for (int ks = 0; ks < 4; ++ks) {
      int k0 = ks * 32 + quad * 8;
      bf16x8 ah[2], al[2];
      #pragma unroll
      for (int mt = 0; mt < 2; ++mt) {
        int row = r0 + mt * 16 + l15;
        row = (row < N_NODES) ? row : (N_NODES - 1);
        const float* xp = x + (size_t)row * DIM + k0;
        float xv[8];
        *(float4*)(xv)     = *(const float4*)(xp);
        *(float4*)(xv + 4) = *(const float4*)(xp + 4);
        #pragma unroll
        for (int j = 0; j < 8; ++j) {
          unsigned short h = f2bf(xv[j]);
          ah[mt][j] = (short)h;
          al[mt][j] = (short)f2bf(xv[j] - bf2f(h));
        }
      }
      #pragma unroll
      for (int nt = 0; nt < 8; ++nt) {
        U bh, bl;
        bh.u = *(const uint4*)(W1th + (nt * 16 + l15) * DIM + k0);
        bl.u = *(const uint4*)(W1tl + (nt * 16 + l15) * DIM + k0);
        #pragma unroll
        for (int mt = 0; mt < 2; ++mt) {
          acc[mt][nt] = __builtin_amdgcn_mfma_f32_16x16x32_bf16(ah[mt], bh.h, acc[mt][nt], 0, 0, 0);
          acc[mt][nt] = __builtin_amdgcn_mfma_f32_16x16x32_bf16(al[mt], bh.h, acc[mt][nt], 0, 0, 0);
          acc[mt][nt] = __builtin_amdgcn_mfma_f32_16x16x32_bf16(ah[mt], bl.h, acc[mt][nt], 0, 0, 0);
        }
      }
    }
    #pragma unroll
    for (int mt = 0; mt < 2; ++mt)
      #pragma unroll
      for (int reg = 0; reg < 4; ++reg) {
        int row = r0 + mt * 16 + quad * 4 + reg;
        if (row < N_NODES) {
          #pragma unroll
          for (int nt = 0; nt < 8; ++nt)
            hout[(size_t)row * DIM + nt * 16 + l15] = f2bf(acc[mt][nt][reg]);
        }
      }
  } else if (bid < G_GEMM + G_TQ) {
    // ---- decoder precompute: T_r = Rel_r @ M (LDS), Q_r = T_r @ Rel_r^T ----
    int rb = bid - G_GEMM;
    int r = rb >> 1, dblk = rb & 1;
    const float* Rr = Rel + (size_t)r * DIM * DIM;
    unsigned short* Qr = Qbf + (size_t)r * DIM * DIM;
    int dw = dblk * 64 + wave * 16;
    f32x4 acc[8];
    #pragma unroll
    for (int nt = 0; nt < 8; ++nt) acc[nt] = f32x4{0.f, 0.f, 0.f, 0.f};
    #pragma unroll
    for (int ks = 0; ks < 4; ++ks) {
      int k0 = ks * 32 + quad * 8;
      const float* ap = Rr + (size_t)(dw + l15) * DIM + k0;
      float av[8];
      *(float4*)(av)     = *(const float4*)(ap);
      *(float4*)(av + 4) = *(const float4*)(ap + 4);
      bf16x8 a;
      #pragma unroll
      for (int j = 0; j < 8; ++j) a[j] = (short)f2bf(av[j]);
      #pragma unroll
      for (int nt = 0; nt < 8; ++nt) {
        U b; b.u = *(const uint4*)(Mth + (nt * 16 + l15) * DIM + k0);
        acc[nt] = __builtin_amdgcn_mfma_f32_16x16x32_bf16(a, b.h, acc[nt], 0, 0, 0);
      }
    }
    #pragma unroll
    for (int nt = 0; nt < 8; ++nt)
      #pragma unroll
      for (int reg = 0; reg < 4; ++reg)
        Ts[(wave * 16 + quad * 4 + reg) * TPAD + nt * 16 + l15] = f2bf(acc[nt][reg]);
    __syncthreads();
    f32x4 qacc[8];
    #pragma unroll
    for (int nt = 0; nt < 8; ++nt) qacc[nt] = f32x4{0.f, 0.f, 0.f, 0.f};
    #pragma unroll
    for (int ks = 0; ks < 4; ++ks) {
      int k0 = ks * 32 + quad * 8;
      U a; a.u = *(const uint4*)(Ts + (wave * 16 + l15) * TPAD + k0);
      #pragma unroll
      for (int nt = 0; nt < 8; ++nt) {
        const float* bp = Rr + (size_t)(nt * 16 + l15) * DIM + k0;
        float bv[8];
        *(float4*)(bv)     = *(const float4*)(bp);
        *(float4*)(bv + 4) = *(const float4*)(bp + 4);
        bf16x8 b;
        #pragma unroll
        for (int j = 0; j < 8; ++j) b[j] = (short)f2bf(bv[j]);
        qacc[nt] = __builtin_amdgcn_mfma_f32_16x16x32_bf16(a.h, b, qacc[nt], 0, 0, 0);
      }
    }
    #pragma unroll
    for (int nt = 0; nt < 8; ++nt)
      #pragma unroll
      for (int reg = 0; reg < 4; ++reg)
        Qr[(size_t)(dw + quad * 4 + reg) * DIM + nt * 16 + l15] = f2bf(qacc[nt][reg]);
  } else {
    // ---- edge degree count: 4 edges/thread ----
    int cb = bid - (G_GEMM + G_TQ);
    int i0 = cb * 1024 + threadIdx.x * 4;
    if (i0 < N_EDGES) {
      int4 d4 = *(const int4*)(dst + i0);
      atomicAdd(&cnt[d4.x], 1);
      atomicAdd(&cnt[d4.y], 1);
      atomicAdd(&cnt[d4.z], 1);
      atomicAdd(&cnt[d4.w], 1);
    }
  }
}

// ---------------- scan reduce + dinv ----------------

__global__ __launch_bounds__(256) void k_scanred_dinv(const int* __restrict__ cnt, int* __restrict__ bsum,
                                                      float* __restrict__ dinv) {
  __shared__ int sd[256];
  int base = blockIdx.x * 1024;
  int t = threadIdx.x;
  int s = 0;
  #pragma unroll
  for (int i = 0; i < 4; ++i) {
    int idx = base + t * 4 + i;
    if (idx < N_NODES) {
      int c = cnt[idx];
      s += c;
      dinv[idx] = rsqrtf((float)(c + 1));
    }
  }
  sd[t] = s; __syncthreads();
  for (int off = 128; off > 0; off >>= 1) {
    if (t < off) sd[t] += sd[t + off];
    __syncthreads();
  }
  if (t == 0) bsum[blockIdx.x] = sd[0];
}

__global__ void k_scan_bsum(int* __restrict__ bsum, int* __restrict__ rowptr_end, int nb) {
  if (threadIdx.x == 0 && blockIdx.x == 0) {
    int acc = 0;
    for (int i = 0; i < nb; ++i) { int v = bsum[i]; bsum[i] = acc; acc += v; }
    *rowptr_end = acc;
  }
}

// writes rowptr AND cursor (cursor starts at rowptr)
__global__ __launch_bounds__(256) void k_scan_scatter(const int* __restrict__ cnt, const int* __restrict__ bsum,
                                                      int* __restrict__ rowptr, int* __restrict__ cursor) {
  __shared__ int sd[256];
  int base = blockIdx.x * 1024;
  int t = threadIdx.x;
  int v[4]; int s = 0;
  #pragma unroll
  for (int i = 0; i < 4; ++i) {
    int idx = base + t * 4 + i;
    v[i] = (idx < N_NODES) ? cnt[idx] : 0;
    s += v[i];
  }
  sd[t] = s; __syncthreads();
  for (int off = 1; off < 256; off <<= 1) {
    int y = (t >= off) ? sd[t - off] : 0;
    __syncthreads();
    sd[t] += y;
    __syncthreads();
  }
  int pre = bsum[blockIdx.x] + sd[t] - s;
  #pragma unroll
  for (int i = 0; i < 4; ++i) {
    int idx = base + t * 4 + i;
    if (idx < N_NODES) { rowptr[idx] = pre; cursor[idx] = pre; }
    pre += v[i];
  }
}

// ---------------- fill: 4 edges/thread, cursor gives absolute slot ----------------

__global__ __launch_bounds__(256) void k_fill(const int* __restrict__ src, const int* __restrict__ dst,
                                              int* __restrict__ cursor, int* __restrict__ esrc) {
  int i0 = blockIdx.x * 1024 + threadIdx.x * 4;
  if (i0 >= N_EDGES) return;
  int4 s4 = *(const int4*)(src + i0);
  int4 d4 = *(const int4*)(dst + i0);
  esrc[atomicAdd(&cursor[d4.x], 1)] = s4.x;
  esrc[atomicAdd(&cursor[d4.y], 1)] = s4.y;
  esrc[atomicAdd(&cursor[d4.z], 1)] = s4.z;
  esrc[atomicAdd(&cursor[d4.w], 1)] = s4.w;
}

// ---------------- GCN aggregate: half-wave per node, bf16 h rows, 4-edge unroll ----------------

__global__ __launch_bounds__(256) void k_agg(const unsigned short* __restrict__ h, const int* __restrict__ rowptr,
                                             const int* __restrict__ esrc, const float* __restrict__ dinv,
                                             const float* __restrict__ bias, float* __restrict__ out) {
  int node = blockIdx.x * 8 + (threadIdx.x >> 5);
  if (node >= N_NODES) return;
  int lane = threadIdx.x & 31;
  const ushort4* h4 = (const ushort4*)h;
  float di = dinv[node];
  ushort4 hv = h4[(size_t)node * 32 + lane];
  float ax = di * bf2f(hv.x), ay = di * bf2f(hv.y), az = di * bf2f(hv.z), aw = di * bf2f(hv.w);
  int e = rowptr[node], end = rowptr[node + 1];
  for (; e + 3 < end; e += 4) {
    int s0 = esrc[e], s1 = esrc[e + 1], s2 = esrc[e + 2], s3 = esrc[e + 3];
    float d0 = dinv[s0], d1 = dinv[s1], d2 = dinv[s2], d3 = dinv[s3];
    ushort4 v0 = h4[(size_t)s0 * 32 + lane];
    ushort4 v1 = h4[(size_t)s1 * 32 + lane];
    ushort4 v2 = h4[(size_t)s2 * 32 + lane];
    ushort4 v3 = h4[(size_t)s3 * 32 + lane];
    ax = fmaf(d0, bf2f(v0.x), ax); ay = fmaf(d0, bf2f(v0.y), ay); az = fmaf(d0, bf2f(v0.z), az); aw = fmaf(d0, bf2f(v0.w), aw);
    ax = fmaf(d1, bf2f(v1.x), ax); ay = fmaf(d1, bf2f(v1.y), ay); az = fmaf(d1, bf2f(v1.z), az); aw = fmaf(d1, bf2f(v1.w), aw);
    ax = fmaf(d2, bf2f(v2.x), ax); ay = fmaf(d2, bf2f(v2.y), ay); az = fmaf(d2, bf2f(v2.z), az); aw = fmaf(d2, bf2f(v2.w), aw);
    ax = fmaf(d3, bf2f(v3.x), ax); ay = fmaf(d3, bf2f(v3.y), ay); az = fmaf(d3, bf2f(v3.z), az); aw = fmaf(d3, bf2f(v3.w), aw);
  }
  for (; e < end; ++e) {
    int s = esrc[e];
    float ds = dinv[s];
    ushort4 vs = h4[(size_t)s * 32 + lane];
    ax = fmaf(ds, bf2f(vs.x), ax); ay = fmaf(ds, bf2f(vs.y), ay);
    az = fmaf(ds, bf2f(vs.z), az); aw = fmaf(ds, bf2f(vs.w), aw);
  }
  float4 bb = ((const float4*)bias)[lane];
  float4 o;
  o.x = fmaf(di, ax, bb.x); o.y = fmaf(di, ay, bb.y);
  o.z = fmaf(di, az, bb.z); o.w = fmaf(di, aw, bb.w);
  ((float4*)out)[(size_t)node * 32 + lane] = o;
}

// ---------------- node GEMM layer 2 (standalone) ----------------

__global__ __launch_bounds__(256) void k_gemm_mfma(const float* __restrict__ x,
                                                   const unsigned short* __restrict__ Wth,
                                                   const unsigned short* __restrict__ Wtl,
                                                   unsigned short* __restrict__ out, int nrows) {
  int wave = threadIdx.x >> 6, lane = threadIdx.x & 63;
  int l15 = lane & 15, quad = lane >> 4;
  int r0 = blockIdx.x * 128 + wave * 32;
  f32x4 acc[2][8];
  #pragma unroll
  for (int mt = 0; mt < 2; ++mt)
    #pragma unroll
    for (int nt = 0; nt < 8; ++nt) acc[mt][nt] = f32x4{0.f, 0.f, 0.f, 0.f};
  union U { uint4 u; bf16x8 h; };
  #pragma unroll
  for (int ks = 0; ks < 4; ++ks) {
    int k0 = ks * 32 + quad * 8;
    bf16x8 ah[2], al[2];
    #pragma unroll
    for (int mt = 0; mt < 2; ++mt) {
      int row = r0 + mt * 16 + l15;
      row = (row < nrows) ? row : (nrows - 1);
      const float* xp = x + (size_t)row * DIM + k0;
      float xv[8];
      *(float4*)(xv)     = *(const float4*)(xp);
      *(float4*)(xv + 4) = *(const float4*)(xp + 4);
      #pragma unroll
      for (int j = 0; j < 8; ++j) {
        unsigned short h = f2bf(xv[j]);
        ah[mt][j] = (short)h;
        al[mt][j] = (short)f2bf(xv[j] - bf2f(h));
      }
    }
    #pragma unroll
    for (int nt = 0; nt < 8; ++nt) {
      U bh, bl;
      bh.u = *(const uint4*)(Wth + (nt * 16 + l15) * DIM + k0);
      bl.u = *(const uint4*)(Wtl + (nt * 16 + l15) * DIM + k0);
      #pragma unroll
      for (int mt = 0; mt < 2; ++mt) {
        acc[mt][nt] = __builtin_amdgcn_mfma_f32_16x16x32_bf16(ah[mt], bh.h, acc[mt][nt], 0, 0, 0);
        acc[mt][nt] = __builtin_amdgcn_mfma_f32_16x16x32_bf16(al[mt], bh.h, acc[mt][nt], 0, 0, 0);
        acc[mt][nt] = __builtin_amdgcn_mfma_f32_16x16x32_bf16(ah[mt], bl.h, acc[mt][nt], 0, 0, 0);
      }
    }
  }
  #pragma unroll
  for (int mt = 0; mt < 2; ++mt)
    #pragma unroll
    for (int reg = 0; reg < 4; ++reg) {
      int row = r0 + mt * 16 + quad * 4 + reg;
      if (row < nrows) {
        #pragma unroll
        for (int nt = 0; nt < 8; ++nt)
          out[(size_t)row * DIM + nt * 16 + l15] = f2bf(acc[mt][nt][reg]);
      }
    }
}

// ---------------- predict via MFMA, inline gather from bufB ----------------

#define QPAD 136

__global__ __launch_bounds__(256) void k_predict_mfma(const float* __restrict__ xfin,
                                                      const int* __restrict__ head,
                                                      const int* __restrict__ tail,
                                                      const unsigned short* __restrict__ Qbf,
                                                      float* __restrict__ out) {
  __shared__ __align__(16) unsigned short Qs[DIM * QPAD];
  __shared__ int Hidx[128];
  __shared__ int Tidx[128];
  int r = blockIdx.y;
  const unsigned short* Qr = Qbf + (size_t)r * DIM * DIM;
  for (int i = threadIdx.x; i < DIM * DIM / 8; i += 256) {
    int d = i >> 4, c = (i & 15) * 8;
    uint4 v = ((const uint4*)Qr)[i];
    *(uint4*)(&Qs[d * QPAD + c]) = v;
  }
  if (threadIdx.x < 128) Hidx[threadIdx.x] = head[blockIdx.x * 128 + threadIdx.x];
  else Tidx[threadIdx.x - 128] = tail[blockIdx.x * 128 + threadIdx.x - 128];
  __syncthreads();
  int wave = threadIdx.x >> 6, lane = threadIdx.x & 63;
  int l15 = lane & 15, quad = lane >> 4;
  int t0r = Tidx[wave * 32 + l15];
  int t1r = Tidx[wave * 32 + 16 + l15];

  f32x4 acc[2][8];
  #pragma unroll
  for (int m = 0; m < 2; ++m)
    #pragma unroll
    for (int n = 0; n < 8; ++n) acc[m][n] = f32x4{0.f, 0.f, 0.f, 0.f};

  union U { uint4 u; bf16x8 h; };
  #pragma unroll
  for (int ks = 0; ks < 4; ++ks) {
    int eoff = ks * 32 + quad * 8;
    float tv0[8], tv1[8];
    *(float4*)(tv0)     = *(const float4*)(xfin + (size_t)t0r * DIM + eoff);
    *(float4*)(tv0 + 4) = *(const float4*)(xfin + (size_t)t0r * DIM + eoff + 4);
    *(float4*)(tv1)     = *(const float4*)(xfin + (size_t)t1r * DIM + eoff);
    *(float4*)(tv1 + 4) = *(const float4*)(xfin + (size_t)t1r * DIM + eoff + 4);
    bf16x8 a0, a1;
    #pragma unroll
    for (int j = 0; j < 8; ++j) { a0[j] = (short)f2bf(tv0[j]); a1[j] = (short)f2bf(tv1[j]); }
    #pragma unroll
    for (int nt = 0; nt < 8; ++nt) {
      U b; b.u = *(const uint4*)(&Qs[(nt * 16 + l15) * QPAD + eoff]);
      acc[0][nt] = __builtin_amdgcn_mfma_f32_16x16x32_bf16(a0, b.h, acc[0][nt], 0, 0, 0);
      acc[1][nt] = __builtin_amdgcn_mfma_f32_16x16x32_bf16(a1, b.h, acc[1][nt], 0, 0, 0);
    }
  }

  int bbase = blockIdx.x * 128 + wave * 32;
  #pragma unroll
  for (int m = 0; m < 2; ++m) {
    #pragma unroll
    for (int reg = 0; reg < 4; ++reg) {
      int bl = wave * 32 + m * 16 + quad * 4 + reg;
      int hrow = Hidx[bl];
      float s = 0.f;
      #pragma unroll
      for (int nt = 0; nt < 8; ++nt)
        s += xfin[(size_t)hrow * DIM + nt * 16 + l15] * acc[m][nt][reg];
      #pragma unroll
      for (int off = 1; off < 16; off <<= 1) s += __shfl_xor(s, off, 64);
      if (l15 == 0) out[(size_t)(bbase + m * 16 + quad * 4 + reg) * N_REL + r] = s;
    }
  }
}

// ---------------- launch ----------------

extern "C" void kernel_launch(void* const* d_in, const int* in_sizes, int n_in,
                              void* d_out, int out_size, void* d_ws, size_t ws_size,
                              hipStream_t stream) {
  (void)in_sizes; (void)n_in; (void)out_size; (void)ws_size;
  const float* init_emb = (const float*)d_in[0];
  const float* W1  = (const float*)d_in[1];
  const float* b1  = (const float*)d_in[2];
  const float* W2  = (const float*)d_in[3];
  const float* b2  = (const float*)d_in[4];
  const float* Rel = (const float*)d_in[5];
  const float* M   = (const float*)d_in[6];
  const int* head  = (const int*)d_in[7];
  const int* tail  = (const int*)d_in[8];
  const int* src   = (const int*)d_in[9];
  const int* dst   = src + N_EDGES;
  float* out = (float*)d_out;

  char* p = (char*)d_ws;
  auto alloc = [&](size_t bytes) { char* q = p; p += (bytes + 511) & ~(size_t)511; return q; };
  int*   cnt    = (int*)alloc((size_t)N_NODES * 4);
  int*   cursor = (int*)alloc((size_t)N_NODES * 4);
  int*   rowptr = (int*)alloc((size_t)(N_NODES + 1) * 4);
  int*   bsum   = (int*)alloc(64 * 4);
  int*   esrc   = (int*)alloc((size_t)N_EDGES * 4);
  float* dinv   = (float*)alloc((size_t)N_NODES * 4);
  unsigned short* hbuf = (unsigned short*)alloc((size_t)N_NODES * DIM * 2);
  float* bufB   = (float*)alloc((size_t)N_NODES * DIM * 4);
  unsigned short* Qbf   = (unsigned short*)alloc((size_t)N_REL * DIM * DIM * 2);
  unsigned short* W1th  = (unsigned short*)alloc((size_t)DIM * DIM * 2);
  unsigned short* W1tl  = (unsigned short*)alloc((size_t)DIM * DIM * 2);
  unsigned short* W2th  = (unsigned short*)alloc((size_t)DIM * DIM * 2);
  unsigned short* W2tl  = (unsigned short*)alloc((size_t)DIM * DIM * 2);
  unsigned short* Mth   = (unsigned short*)alloc((size_t)DIM * DIM * 2);

  // 0: zero cnt + weight prep
  k_prep_zero<<<256, 256, 0, stream>>>(W1, W2, M, W1th, W1tl, W2th, W2tl, Mth, cnt);
  // 1: gemm1 || decoder TQ || edge count
  k_mega1<<<G_GEMM + G_TQ + G_CNT, 256, 0, stream>>>(init_emb, W1th, W1tl, hbuf,
                                                     Rel, Mth, Qbf, dst, cnt);
  // 2-4: scan chain (dinv fused; cursor initialized with rowptr)
  int nb = (N_NODES + 1023) / 1024;  // 49
  k_scanred_dinv<<<nb, 256, 0, stream>>>(cnt, bsum, dinv);
  k_scan_bsum<<<1, 64, 0, stream>>>(bsum, rowptr + N_NODES, nb);
  k_scan_scatter<<<nb, 256, 0, stream>>>(cnt, bsum, rowptr, cursor);
  // 5: CSR fill
  k_fill<<<G_CNT, 256, 0, stream>>>(src, dst, cursor, esrc);
  // 6-8: agg1, gemm2, agg2
  k_agg<<<(N_NODES + 7) / 8, 256, 0, stream>>>(hbuf, rowptr, esrc, dinv, b1, bufB);
  k_gemm_mfma<<<(N_NODES + 127) / 128, 256, 0, stream>>>(bufB, W2th, W2tl, hbuf, N_NODES);
  k_agg<<<(N_NODES + 7) / 8, 256, 0, stream>>>(hbuf, rowptr, esrc, dinv, b2, bufB);
  // 9: predict (inline gather)
  k_predict_mfma<<<dim3(BATCH / 128, N_REL), 256, 0, stream>>>(bufB, head, tail, Qbf, out);
}

// Round 8
// 317.379 us; speedup vs baseline: 4.3080x; 1.0037x over previous
//
#include <hip/hip_runtime.h>

#define N_NODES 50000
#define N_EDGES 800000
#define DIM 128
#define N_REL 86
#define BATCH 2048

using bf16x8 = __attribute__((ext_vector_type(8))) short;
using f32x4  = __attribute__((ext_vector_type(4))) float;

// float -> bf16 round-to-nearest-even (finite inputs)
static __device__ __forceinline__ unsigned short f2bf(float f) {
  union { float f; unsigned int i; } v; v.f = f;
  unsigned int x = v.i;
  unsigned int r = x + 0x7FFFu + ((x >> 16) & 1u);
  return (unsigned short)(r >> 16);
}
static __device__ __forceinline__ float bf2f(unsigned short u) {
  union { unsigned int i; float f; } v;
  v.i = ((unsigned int)u) << 16;
  return v.f;
}

#define G_EDGE4 782           // ceil(800000/1024), 4 edges/thread
#define G_TQ    172           // 86 relations x 2 d-blocks
#define G_GEMM  391           // ceil(50000/128)
#define TPAD 136              // 128+8 bf16: 272 B row stride -> 2-way bank alias (free)

// ---------------- kernel 0: zero cnt + weight prep ----------------

__global__ __launch_bounds__(256) void k_prep_zero(const float* __restrict__ W1, const float* __restrict__ W2,
                                                   const float* __restrict__ M,
                                                   unsigned short* __restrict__ W1th, unsigned short* __restrict__ W1tl,
                                                   unsigned short* __restrict__ W2th, unsigned short* __restrict__ W2tl,
                                                   unsigned short* __restrict__ Mth,
                                                   int* __restrict__ cnt) {
  int g = blockIdx.x * 256 + threadIdx.x;          // 65536 threads
  if (g < N_NODES) cnt[g] = 0;
  if (g < DIM * DIM) {
    int k = g >> 7, n = g & 127;
    int t = n * DIM + k;
    float w1 = W1[g];
    unsigned short h1 = f2bf(w1);
    W1th[t] = h1;
    W1tl[t] = f2bf(w1 - bf2f(h1));
    float w2 = W2[g];
    unsigned short h2 = f2bf(w2);
    W2th[t] = h2;
    W2tl[t] = f2bf(w2 - bf2f(h2));
    Mth[t] = f2bf(M[g]);
  }
}

// ---------------- megaA: edge count (+epos)  ||  decoder TQ ----------------

__global__ __launch_bounds__(256) void k_megaA(const int* __restrict__ dst,
                                               int* __restrict__ cnt, int* __restrict__ epos,
                                               const float* __restrict__ Rel,
                                               const unsigned short* __restrict__ Mth,
                                               unsigned short* __restrict__ Qbf) {
  __shared__ __align__(16) unsigned short Ts[64 * TPAD];
  int bid = blockIdx.x;
  int wave = threadIdx.x >> 6, lane = threadIdx.x & 63;
  int l15 = lane & 15, quad = lane >> 4;
  union U { uint4 u; bf16x8 h; };

  if (bid < G_EDGE4) {
    // ---- edge degree count, record per-edge slot ----
    int i0 = bid * 1024 + threadIdx.x * 4;
    if (i0 < N_EDGES) {
      int4 d4 = *(const int4*)(dst + i0);
      int4 e4;
      e4.x = atomicAdd(&cnt[d4.x], 1);
      e4.y = atomicAdd(&cnt[d4.y], 1);
      e4.z = atomicAdd(&cnt[d4.z], 1);
      e4.w = atomicAdd(&cnt[d4.w], 1);
      *(int4*)(epos + i0) = e4;
    }
  } else {
    // ---- decoder precompute: T_r = Rel_r @ M (LDS), Q_r = T_r @ Rel_r^T ----
    int rb = bid - G_EDGE4;
    int r = rb >> 1, dblk = rb & 1;
    const float* Rr = Rel + (size_t)r * DIM * DIM;
    unsigned short* Qr = Qbf + (size_t)r * DIM * DIM;
    int dw = dblk * 64 + wave * 16;
    f32x4 acc[8];
    #pragma unroll
    for (int nt = 0; nt < 8; ++nt) acc[nt] = f32x4{0.f, 0.f, 0.f, 0.f};
    #pragma unroll
    for (int ks = 0; ks < 4; ++ks) {
      int k0 = ks * 32 + quad * 8;
      const float* ap = Rr + (size_t)(dw + l15) * DIM + k0;
      float av[8];
      *(float4*)(av)     = *(const float4*)(ap);
      *(float4*)(av + 4) = *(const float4*)(ap + 4);
      bf16x8 a;
      #pragma unroll
      for (int j = 0; j < 8; ++j) a[j] = (short)f2bf(av[j]);
      #pragma unroll
      for (int nt = 0; nt < 8; ++nt) {
        U b; b.u = *(const uint4*)(Mth + (nt * 16 + l15) * DIM + k0);
        acc[nt] = __builtin_amdgcn_mfma_f32_16x16x32_bf16(a, b.h, acc[nt], 0, 0, 0);
      }
    }
    #pragma unroll
    for (int nt = 0; nt < 8; ++nt)
      #pragma unroll
      for (int reg = 0; reg < 4; ++reg)
        Ts[(wave * 16 + quad * 4 + reg) * TPAD + nt * 16 + l15] = f2bf(acc[nt][reg]);
    __syncthreads();
    f32x4 qacc[8];
    #pragma unroll
    for (int nt = 0; nt < 8; ++nt) qacc[nt] = f32x4{0.f, 0.f, 0.f, 0.f};
    #pragma unroll
    for (int ks = 0; ks < 4; ++ks) {
      int k0 = ks * 32 + quad * 8;
      U a; a.u = *(const uint4*)(Ts + (wave * 16 + l15) * TPAD + k0);
      #pragma unroll
      for (int nt = 0; nt < 8; ++nt) {
        const float* bp = Rr + (size_t)(nt * 16 + l15) * DIM + k0;
        float bv[8];
        *(float4*)(bv)     = *(const float4*)(bp);
        *(float4*)(bv + 4) = *(const float4*)(bp + 4);
        bf16x8 b;
        #pragma unroll
        for (int j = 0; j < 8; ++j) b[j] = (short)f2bf(bv[j]);
        qacc[nt] = __builtin_amdgcn_mfma_f32_16x16x32_bf16(a.h, b, qacc[nt], 0, 0, 0);
      }
    }
    #pragma unroll
    for (int nt = 0; nt < 8; ++nt)
      #pragma unroll
      for (int reg = 0; reg < 4; ++reg)
        Qr[(size_t)(dw + quad * 4 + reg) * DIM + nt * 16 + l15] = f2bf(qacc[nt][reg]);
  }
}

// ---------------- scan reduce + dinv ----------------

__global__ __launch_bounds__(256) void k_scanred_dinv(const int* __restrict__ cnt, int* __restrict__ bsum,
                                                      float* __restrict__ dinv) {
  __shared__ int sd[256];
  int base = blockIdx.x * 1024;
  int t = threadIdx.x;
  int s = 0;
  #pragma unroll
  for (int i = 0; i < 4; ++i) {
    int idx = base + t * 4 + i;
    if (idx < N_NODES) {
      int c = cnt[idx];
      s += c;
      dinv[idx] = rsqrtf((float)(c + 1));
    }
  }
  sd[t] = s; __syncthreads();
  for (int off = 128; off > 0; off >>= 1) {
    if (t < off) sd[t] += sd[t + off];
    __syncthreads();
  }
  if (t == 0) bsum[blockIdx.x] = sd[0];
}

__global__ void k_scan_bsum(int* __restrict__ bsum, int* __restrict__ rowptr_end, int nb) {
  if (threadIdx.x == 0 && blockIdx.x == 0) {
    int acc = 0;
    for (int i = 0; i < nb; ++i) { int v = bsum[i]; bsum[i] = acc; acc += v; }
    *rowptr_end = acc;
  }
}

__global__ __launch_bounds__(256) void k_scan_scatter(const int* __restrict__ cnt, const int* __restrict__ bsum,
                                                      int* __restrict__ rowptr) {
  __shared__ int sd[256];
  int base = blockIdx.x * 1024;
  int t = threadIdx.x;
  int v[4]; int s = 0;
  #pragma unroll
  for (int i = 0; i < 4; ++i) {
    int idx = base + t * 4 + i;
    v[i] = (idx < N_NODES) ? cnt[idx] : 0;
    s += v[i];
  }
  sd[t] = s; __syncthreads();
  for (int off = 1; off < 256; off <<= 1) {
    int y = (t >= off) ? sd[t - off] : 0;
    __syncthreads();
    sd[t] += y;
    __syncthreads();
  }
  int pre = bsum[blockIdx.x] + sd[t] - s;
  #pragma unroll
  for (int i = 0; i < 4; ++i) {
    int idx = base + t * 4 + i;
    if (idx < N_NODES) rowptr[idx] = pre;
    pre += v[i];
  }
}

// ---------------- megaB: CSR fill (no atomics)  ||  gemm1 ----------------

__global__ __launch_bounds__(256) void k_megaB(const int* __restrict__ src, const int* __restrict__ dst,
                                               const int* __restrict__ rowptr, const int* __restrict__ epos,
                                               int* __restrict__ esrc,
                                               const float* __restrict__ x,
                                               const unsigned short* __restrict__ W1th,
                                               const unsigned short* __restrict__ W1tl,
                                               unsigned short* __restrict__ hout) {
  int bid = blockIdx.x;
  union U { uint4 u; bf16x8 h; };
  if (bid < G_EDGE4) {
    // ---- fill: plain scatter, slot = rowptr[d] + epos ----
    int i0 = bid * 1024 + threadIdx.x * 4;
    if (i0 < N_EDGES) {
      int4 s4 = *(const int4*)(src + i0);
      int4 d4 = *(const int4*)(dst + i0);
      int4 e4 = *(const int4*)(epos + i0);
      esrc[rowptr[d4.x] + e4.x] = s4.x;
      esrc[rowptr[d4.y] + e4.y] = s4.y;
      esrc[rowptr[d4.z] + e4.z] = s4.z;
      esrc[rowptr[d4.w] + e4.w] = s4.w;
    }
  } else {
    // ---- node GEMM layer 1: hout = x @ W1 (hi/lo 3-term, bf16 out) ----
    int wave = threadIdx.x >> 6, lane = threadIdx.x & 63;
    int l15 = lane & 15, quad = lane >> 4;
    int r0 = (bid - G_EDGE4) * 128 + wave * 32;
    f32x4 acc[2][8];
    #pragma unroll
    for (int mt = 0; mt < 2; ++mt)
      #pragma unroll
      for (int nt = 0; nt < 8; ++nt) acc[mt][nt] = f32x4{0.f, 0.f, 0.f, 0.f};
    #pragma unroll
    for (int ks = 0; ks < 4; ++ks) {
      int k0 = ks * 32 + quad * 8;
      bf16x8 ah[2], al[2];
      #pragma unroll
      for (int mt = 0; mt < 2; ++mt) {
        int row = r0 + mt * 16 + l15;
        row = (row < N_NODES) ? row : (N_NODES - 1);
        const float* xp = x + (size_t)row * DIM + k0;
        float xv[8];
        *(float4*)(xv)     = *(const float4*)(xp);
        *(float4*)(xv + 4) = *(const float4*)(xp + 4);
        #pragma unroll
        for (int j = 0; j < 8; ++j) {
          unsigned short h = f2bf(xv[j]);
          ah[mt][j] = (short)h;
          al[mt][j] = (short)f2bf(xv[j] - bf2f(h));
        }
      }
      #pragma unroll
      for (int nt = 0; nt < 8; ++nt) {
        U bh, bl;
        bh.u = *(const uint4*)(W1th + (nt * 16 + l15) * DIM + k0);
        bl.u = *(const uint4*)(W1tl + (nt * 16 + l15) * DIM + k0);
        #pragma unroll
        for (int mt = 0; mt < 2; ++mt) {
          acc[mt][nt] = __builtin_amdgcn_mfma_f32_16x16x32_bf16(ah[mt], bh.h, acc[mt][nt], 0, 0, 0);
          acc[mt][nt] = __builtin_amdgcn_mfma_f32_16x16x32_bf16(al[mt], bh.h, acc[mt][nt], 0, 0, 0);
          acc[mt][nt] = __builtin_amdgcn_mfma_f32_16x16x32_bf16(ah[mt], bl.h, acc[mt][nt], 0, 0, 0);
        }
      }
    }
    #pragma unroll
    for (int mt = 0; mt < 2; ++mt)
      #pragma unroll
      for (int reg = 0; reg < 4; ++reg) {
        int row = r0 + mt * 16 + quad * 4 + reg;
        if (row < N_NODES) {
          #pragma unroll
          for (int nt = 0; nt < 8; ++nt)
            hout[(size_t)row * DIM + nt * 16 + l15] = f2bf(acc[mt][nt][reg]);
        }
      }
  }
}

// ---------------- fused agg1 + gemm2: 64 nodes/block, agg result via LDS hi/lo ----------------

__global__ __launch_bounds__(256) void k_agg_gemm(const unsigned short* __restrict__ hin,
                                                  const int* __restrict__ rowptr,
                                                  const int* __restrict__ esrc,
                                                  const float* __restrict__ dinv,
                                                  const float* __restrict__ bias,
                                                  const unsigned short* __restrict__ Wth,
                                                  const unsigned short* __restrict__ Wtl,
                                                  unsigned short* __restrict__ hout) {
  __shared__ __align__(16) unsigned short Hs[64 * TPAD];
  __shared__ __align__(16) unsigned short Ls[64 * TPAD];
  int base = blockIdx.x * 64;
  int hw = threadIdx.x >> 5, lane32 = threadIdx.x & 31;
  const ushort4* h4 = (const ushort4*)hin;

  // phase 1: aggregate 64 node rows (half-wave per node, 8 iterations)
  #pragma unroll 1
  for (int it = 0; it < 8; ++it) {
    int n = it * 8 + hw;
    int node = base + n;
    if (node < N_NODES) {
      float di = dinv[node];
      ushort4 hv = h4[(size_t)node * 32 + lane32];
      float ax = di * bf2f(hv.x), ay = di * bf2f(hv.y), az = di * bf2f(hv.z), aw = di * bf2f(hv.w);
      int e = rowptr[node], end = rowptr[node + 1];
      for (; e + 3 < end; e += 4) {
        int s0 = esrc[e], s1 = esrc[e + 1], s2 = esrc[e + 2], s3 = esrc[e + 3];
        float d0 = dinv[s0], d1 = dinv[s1], d2 = dinv[s2], d3 = dinv[s3];
        ushort4 v0 = h4[(size_t)s0 * 32 + lane32];
        ushort4 v1 = h4[(size_t)s1 * 32 + lane32];
        ushort4 v2 = h4[(size_t)s2 * 32 + lane32];
        ushort4 v3 = h4[(size_t)s3 * 32 + lane32];
        ax = fmaf(d0, bf2f(v0.x), ax); ay = fmaf(d0, bf2f(v0.y), ay); az = fmaf(d0, bf2f(v0.z), az); aw = fmaf(d0, bf2f(v0.w), aw);
        ax = fmaf(d1, bf2f(v1.x), ax); ay = fmaf(d1, bf2f(v1.y), ay); az = fmaf(d1, bf2f(v1.z), az); aw = fmaf(d1, bf2f(v1.w), aw);
        ax = fmaf(d2, bf2f(v2.x), ax); ay = fmaf(d2, bf2f(v2.y), ay); az = fmaf(d2, bf2f(v2.z), az); aw = fmaf(d2, bf2f(v2.w), aw);
        ax = fmaf(d3, bf2f(v3.x), ax); ay = fmaf(d3, bf2f(v3.y), ay); az = fmaf(d3, bf2f(v3.z), az); aw = fmaf(d3, bf2f(v3.w), aw);
      }
      for (; e < end; ++e) {
        int s = esrc[e];
        float ds = dinv[s];
        ushort4 vs = h4[(size_t)s * 32 + lane32];
        ax = fmaf(ds, bf2f(vs.x), ax); ay = fmaf(ds, bf2f(vs.y), ay);
        az = fmaf(ds, bf2f(vs.z), az); aw = fmaf(ds, bf2f(vs.w), aw);
      }
      float4 bb = ((const float4*)bias)[lane32];
      float vx = fmaf(di, ax, bb.x), vy = fmaf(di, ay, bb.y);
      float vz = fmaf(di, az, bb.z), vw = fmaf(di, aw, bb.w);
      ushort4 hi4, lo4;
      hi4.x = f2bf(vx); lo4.x = f2bf(vx - bf2f(hi4.x));
      hi4.y = f2bf(vy); lo4.y = f2bf(vy - bf2f(hi4.y));
      hi4.z = f2bf(vz); lo4.z = f2bf(vz - bf2f(hi4.z));
      hi4.w = f2bf(vw); lo4.w = f2bf(vw - bf2f(hi4.w));
      *(ushort4*)(&Hs[n * TPAD + lane32 * 4]) = hi4;
      *(ushort4*)(&Ls[n * TPAD + lane32 * 4]) = lo4;
    }
  }
  __syncthreads();

  // phase 2: gemm2 on the 64 LDS rows (wave w -> rows w*16..w*16+15)
  int wave = threadIdx.x >> 6, lane = threadIdx.x & 63;
  int l15 = lane & 15, quad = lane >> 4;
  union U { uint4 u; bf16x8 h; };
  f32x4 acc[8];
  #pragma unroll
  for (int nt = 0; nt < 8; ++nt) acc[nt] = f32x4{0.f, 0.f, 0.f, 0.f};
  #pragma unroll
  for (int ks = 0; ks < 4; ++ks) {
    int k0 = ks * 32 + quad * 8;
    U ah, al;
    ah.u = *(const uint4*)(&Hs[(wave * 16 + l15) * TPAD + k0]);
    al.u = *(const uint4*)(&Ls[(wave * 16 + l15) * TPAD + k0]);
    #pragma unroll
    for (int nt = 0; nt < 8; ++nt) {
      U bh, bl;
      bh.u = *(const uint4*)(Wth + (nt * 16 + l15) * DIM + k0);
      bl.u = *(const uint4*)(Wtl + (nt * 16 + l15) * DIM + k0);
      acc[nt] = __builtin_amdgcn_mfma_f32_16x16x32_bf16(ah.h, bh.h, acc[nt], 0, 0, 0);
      acc[nt] = __builtin_amdgcn_mfma_f32_16x16x32_bf16(al.h, bh.h, acc[nt], 0, 0, 0);
      acc[nt] = __builtin_amdgcn_mfma_f32_16x16x32_bf16(ah.h, bl.h, acc[nt], 0, 0, 0);
    }
  }
  #pragma unroll
  for (int reg = 0; reg < 4; ++reg) {
    int row = base + wave * 16 + quad * 4 + reg;
    if (row < N_NODES) {
      #pragma unroll
      for (int nt = 0; nt < 8; ++nt)
        hout[(size_t)row * DIM + nt * 16 + l15] = f2bf(acc[nt][reg]);
    }
  }
}

// ---------------- agg2: bf16 h rows -> fp32 out ----------------

__global__ __launch_bounds__(256) void k_agg(const unsigned short* __restrict__ h, const int* __restrict__ rowptr,
                                             const int* __restrict__ esrc, const float* __restrict__ dinv,
                                             const float* __restrict__ bias, float* __restrict__ out) {
  int node = blockIdx.x * 8 + (threadIdx.x >> 5);
  if (node >= N_NODES) return;
  int lane = threadIdx.x & 31;
  const ushort4* h4 = (const ushort4*)h;
  float di = dinv[node];
  ushort4 hv = h4[(size_t)node * 32 + lane];
  float ax = di * bf2f(hv.x), ay = di * bf2f(hv.y), az = di * bf2f(hv.z), aw = di * bf2f(hv.w);
  int e = rowptr[node], end = rowptr[node + 1];
  for (; e + 3 < end; e += 4) {
    int s0 = esrc[e], s1 = esrc[e + 1], s2 = esrc[e + 2], s3 = esrc[e + 3];
    float d0 = dinv[s0], d1 = dinv[s1], d2 = dinv[s2], d3 = dinv[s3];
    ushort4 v0 = h4[(size_t)s0 * 32 + lane];
    ushort4 v1 = h4[(size_t)s1 * 32 + lane];
    ushort4 v2 = h4[(size_t)s2 * 32 + lane];
    ushort4 v3 = h4[(size_t)s3 * 32 + lane];
    ax = fmaf(d0, bf2f(v0.x), ax); ay = fmaf(d0, bf2f(v0.y), ay); az = fmaf(d0, bf2f(v0.z), az); aw = fmaf(d0, bf2f(v0.w), aw);
    ax = fmaf(d1, bf2f(v1.x), ax); ay = fmaf(d1, bf2f(v1.y), ay); az = fmaf(d1, bf2f(v1.z), az); aw = fmaf(d1, bf2f(v1.w), aw);
    ax = fmaf(d2, bf2f(v2.x), ax); ay = fmaf(d2, bf2f(v2.y), ay); az = fmaf(d2, bf2f(v2.z), az); aw = fmaf(d2, bf2f(v2.w), aw);
    ax = fmaf(d3, bf2f(v3.x), ax); ay = fmaf(d3, bf2f(v3.y), ay); az = fmaf(d3, bf2f(v3.z), az); aw = fmaf(d3, bf2f(v3.w), aw);
  }
  for (; e < end; ++e) {
    int s = esrc[e];
    float ds = dinv[s];
    ushort4 vs = h4[(size_t)s * 32 + lane];
    ax = fmaf(ds, bf2f(vs.x), ax); ay = fmaf(ds, bf2f(vs.y), ay);
    az = fmaf(ds, bf2f(vs.z), az); aw = fmaf(ds, bf2f(vs.w), aw);
  }
  float4 bb = ((const float4*)bias)[lane];
  float4 o;
  o.x = fmaf(di, ax, bb.x); o.y = fmaf(di, ay, bb.y);
  o.z = fmaf(di, az, bb.z); o.w = fmaf(di, aw, bb.w);
  ((float4*)out)[(size_t)node * 32 + lane] = o;
}

// ---------------- predict via MFMA, inline gather ----------------

#define QPAD 136

__global__ __launch_bounds__(256) void k_predict_mfma(const float* __restrict__ xfin,
                                                      const int* __restrict__ head,
                                                      const int* __restrict__ tail,
                                                      const unsigned short* __restrict__ Qbf,
                                                      float* __restrict__ out) {
  __shared__ __align__(16) unsigned short Qs[DIM * QPAD];
  __shared__ int Hidx[128];
  __shared__ int Tidx[128];
  int r = blockIdx.y;
  const unsigned short* Qr = Qbf + (size_t)r * DIM * DIM;
  for (int i = threadIdx.x; i < DIM * DIM / 8; i += 256) {
    int d = i >> 4, c = (i & 15) * 8;
    uint4 v = ((const uint4*)Qr)[i];
    *(uint4*)(&Qs[d * QPAD + c]) = v;
  }
  if (threadIdx.x < 128) Hidx[threadIdx.x] = head[blockIdx.x * 128 + threadIdx.x];
  else Tidx[threadIdx.x - 128] = tail[blockIdx.x * 128 + threadIdx.x - 128];
  __syncthreads();
  int wave = threadIdx.x >> 6, lane = threadIdx.x & 63;
  int l15 = lane & 15, quad = lane >> 4;
  int t0r = Tidx[wave * 32 + l15];
  int t1r = Tidx[wave * 32 + 16 + l15];

  f32x4 acc[2][8];
  #pragma unroll
  for (int m = 0; m < 2; ++m)
    #pragma unroll
    for (int n = 0; n < 8; ++n) acc[m][n] = f32x4{0.f, 0.f, 0.f, 0.f};

  union U { uint4 u; bf16x8 h; };
  #pragma unroll
  for (int ks = 0; ks < 4; ++ks) {
    int eoff = ks * 32 + quad * 8;
    float tv0[8], tv1[8];
    *(float4*)(tv0)     = *(const float4*)(xfin + (size_t)t0r * DIM + eoff);
    *(float4*)(tv0 + 4) = *(const float4*)(xfin + (size_t)t0r * DIM + eoff + 4);
    *(float4*)(tv1)     = *(const float4*)(xfin + (size_t)t1r * DIM + eoff);
    *(float4*)(tv1 + 4) = *(const float4*)(xfin + (size_t)t1r * DIM + eoff + 4);
    bf16x8 a0, a1;
    #pragma unroll
    for (int j = 0; j < 8; ++j) { a0[j] = (short)f2bf(tv0[j]); a1[j] = (short)f2bf(tv1[j]); }
    #pragma unroll
    for (int nt = 0; nt < 8; ++nt) {
      U b; b.u = *(const uint4*)(&Qs[(nt * 16 + l15) * QPAD + eoff]);
      acc[0][nt] = __builtin_amdgcn_mfma_f32_16x16x32_bf16(a0, b.h, acc[0][nt], 0, 0, 0);
      acc[1][nt] = __builtin_amdgcn_mfma_f32_16x16x32_bf16(a1, b.h, acc[1][nt], 0, 0, 0);
    }
  }

  int bbase = blockIdx.x * 128 + wave * 32;
  #pragma unroll
  for (int m = 0; m < 2; ++m) {
    #pragma unroll
    for (int reg = 0; reg < 4; ++reg) {
      int bl = wave * 32 + m * 16 + quad * 4 + reg;
      int hrow = Hidx[bl];
      float s = 0.f;
      #pragma unroll
      for (int nt = 0; nt < 8; ++nt)
        s += xfin[(size_t)hrow * DIM + nt * 16 + l15] * acc[m][nt][reg];
      #pragma unroll
      for (int off = 1; off < 16; off <<= 1) s += __shfl_xor(s, off, 64);
      if (l15 == 0) out[(size_t)(bbase + m * 16 + quad * 4 + reg) * N_REL + r] = s;
    }
  }
}

// ---------------- launch ----------------

extern "C" void kernel_launch(void* const* d_in, const int* in_sizes, int n_in,
                              void* d_out, int out_size, void* d_ws, size_t ws_size,
                              hipStream_t stream) {
  (void)in_sizes; (void)n_in; (void)out_size; (void)ws_size;
  const float* init_emb = (const float*)d_in[0];
  const float* W1  = (const float*)d_in[1];
  const float* b1  = (const float*)d_in[2];
  const float* W2  = (const float*)d_in[3];
  const float* b2  = (const float*)d_in[4];
  const float* Rel = (const float*)d_in[5];
  const float* M   = (const float*)d_in[6];
  const int* head  = (const int*)d_in[7];
  const int* tail  = (const int*)d_in[8];
  const int* src   = (const int*)d_in[9];
  const int* dst   = src + N_EDGES;
  float* out = (float*)d_out;

  char* p = (char*)d_ws;
  auto alloc = [&](size_t bytes) { char* q = p; p += (bytes + 511) & ~(size_t)511; return q; };
  int*   cnt    = (int*)alloc((size_t)N_NODES * 4);
  int*   rowptr = (int*)alloc((size_t)(N_NODES + 1) * 4);
  int*   bsum   = (int*)alloc(64 * 4);
  int*   esrc   = (int*)alloc((size_t)N_EDGES * 4);
  int*   epos   = (int*)alloc((size_t)N_EDGES * 4);
  float* dinv   = (float*)alloc((size_t)N_NODES * 4);
  unsigned short* hbuf1 = (unsigned short*)alloc((size_t)N_NODES * DIM * 2);
  unsigned short* hbuf2 = (unsigned short*)alloc((size_t)N_NODES * DIM * 2);
  float* bufB   = (float*)alloc((size_t)N_NODES * DIM * 4);
  unsigned short* Qbf   = (unsigned short*)alloc((size_t)N_REL * DIM * DIM * 2);
  unsigned short* W1th  = (unsigned short*)alloc((size_t)DIM * DIM * 2);
  unsigned short* W1tl  = (unsigned short*)alloc((size_t)DIM * DIM * 2);
  unsigned short* W2th  = (unsigned short*)alloc((size_t)DIM * DIM * 2);
  unsigned short* W2tl  = (unsigned short*)alloc((size_t)DIM * DIM * 2);
  unsigned short* Mth   = (unsigned short*)alloc((size_t)DIM * DIM * 2);

  // 0: zero cnt + weight prep
  k_prep_zero<<<256, 256, 0, stream>>>(W1, W2, M, W1th, W1tl, W2th, W2tl, Mth, cnt);
  // 1: count(+epos) || decoder TQ
  k_megaA<<<G_EDGE4 + G_TQ, 256, 0, stream>>>(dst, cnt, epos, Rel, Mth, Qbf);
  // 2-4: scan chain
  int nb = (N_NODES + 1023) / 1024;  // 49
  k_scanred_dinv<<<nb, 256, 0, stream>>>(cnt, bsum, dinv);
  k_scan_bsum<<<1, 64, 0, stream>>>(bsum, rowptr + N_NODES, nb);
  k_scan_scatter<<<nb, 256, 0, stream>>>(cnt, bsum, rowptr);
  // 5: fill (no atomics) || gemm1
  k_megaB<<<G_EDGE4 + G_GEMM, 256, 0, stream>>>(src, dst, rowptr, epos, esrc,
                                                init_emb, W1th, W1tl, hbuf1);
  // 6: fused agg1 + gemm2
  k_agg_gemm<<<(N_NODES + 63) / 64, 256, 0, stream>>>(hbuf1, rowptr, esrc, dinv, b1,
                                                      W2th, W2tl, hbuf2);
  // 7: agg2
  k_agg<<<(N_NODES + 7) / 8, 256, 0, stream>>>(hbuf2, rowptr, esrc, dinv, b2, bufB);
  // 8: predict (inline gather)
  k_predict_mfma<<<dim3(BATCH / 128, N_REL), 256, 0, stream>>>(bufB, head, tail, Qbf, out);
}

// Round 9
// 292.387 us; speedup vs baseline: 4.6762x; 1.0855x over previous
//
#include <hip/hip_runtime.h>

#define N_NODES 50000
#define N_EDGES 800000
#define DIM 128
#define N_REL 86
#define BATCH 2048

using bf16x8 = __attribute__((ext_vector_type(8))) short;
using f32x4  = __attribute__((ext_vector_type(4))) float;

// float -> bf16 round-to-nearest-even (finite inputs)
static __device__ __forceinline__ unsigned short f2bf(float f) {
  union { float f; unsigned int i; } v; v.f = f;
  unsigned int x = v.i;
  unsigned int r = x + 0x7FFFu + ((x >> 16) & 1u);
  return (unsigned short)(r >> 16);
}
static __device__ __forceinline__ float bf2f(unsigned short u) {
  union { unsigned int i; float f; } v;
  v.i = ((unsigned int)u) << 16;
  return v.f;
}

#define G_EDGE4 782           // ceil(800000/1024), 4 edges/thread
#define G_TQ    172           // 86 relations x 2 d-blocks
#define G_GEMM  391           // ceil(50000/128)
#define TPAD 136              // 128+8 bf16: 272 B row stride -> 2-way bank alias (free)

// ---------------- kernel 0: zero cnt + weight prep ----------------

__global__ __launch_bounds__(256) void k_prep_zero(const float* __restrict__ W1, const float* __restrict__ W2,
                                                   const float* __restrict__ M,
                                                   unsigned short* __restrict__ W1th, unsigned short* __restrict__ W1tl,
                                                   unsigned short* __restrict__ W2th, unsigned short* __restrict__ W2tl,
                                                   unsigned short* __restrict__ Mth,
                                                   int* __restrict__ cnt) {
  int g = blockIdx.x * 256 + threadIdx.x;          // 65536 threads
  if (g < N_NODES) cnt[g] = 0;
  if (g < DIM * DIM) {
    int k = g >> 7, n = g & 127;
    int t = n * DIM + k;
    float w1 = W1[g];
    unsigned short h1 = f2bf(w1);
    W1th[t] = h1;
    W1tl[t] = f2bf(w1 - bf2f(h1));
    float w2 = W2[g];
    unsigned short h2 = f2bf(w2);
    W2th[t] = h2;
    W2tl[t] = f2bf(w2 - bf2f(h2));
    Mth[t] = f2bf(M[g]);
  }
}

// ---------------- megaA: edge count (+epos)  ||  decoder TQ ----------------

__global__ __launch_bounds__(256) void k_megaA(const int* __restrict__ dst,
                                               int* __restrict__ cnt, int* __restrict__ epos,
                                               const float* __restrict__ Rel,
                                               const unsigned short* __restrict__ Mth,
                                               unsigned short* __restrict__ Qbf) {
  __shared__ __align__(16) unsigned short Ts[64 * TPAD];
  int bid = blockIdx.x;
  int wave = threadIdx.x >> 6, lane = threadIdx.x & 63;
  int l15 = lane & 15, quad = lane >> 4;
  union U { uint4 u; bf16x8 h; };

  if (bid < G_EDGE4) {
    int i0 = bid * 1024 + threadIdx.x * 4;
    if (i0 < N_EDGES) {
      int4 d4 = *(const int4*)(dst + i0);
      int4 e4;
      e4.x = atomicAdd(&cnt[d4.x], 1);
      e4.y = atomicAdd(&cnt[d4.y], 1);
      e4.z = atomicAdd(&cnt[d4.z], 1);
      e4.w = atomicAdd(&cnt[d4.w], 1);
      *(int4*)(epos + i0) = e4;
    }
  } else {
    // ---- decoder precompute: T_r = Rel_r @ M (LDS), Q_r = T_r @ Rel_r^T ----
    int rb = bid - G_EDGE4;
    int r = rb >> 1, dblk = rb & 1;
    const float* Rr = Rel + (size_t)r * DIM * DIM;
    unsigned short* Qr = Qbf + (size_t)r * DIM * DIM;
    int dw = dblk * 64 + wave * 16;
    f32x4 acc[8];
    #pragma unroll
    for (int nt = 0; nt < 8; ++nt) acc[nt] = f32x4{0.f, 0.f, 0.f, 0.f};
    #pragma unroll
    for (int ks = 0; ks < 4; ++ks) {
      int k0 = ks * 32 + quad * 8;
      const float* ap = Rr + (size_t)(dw + l15) * DIM + k0;
      float av[8];
      *(float4*)(av)     = *(const float4*)(ap);
      *(float4*)(av + 4) = *(const float4*)(ap + 4);
      bf16x8 a;
      #pragma unroll
      for (int j = 0; j < 8; ++j) a[j] = (short)f2bf(av[j]);
      #pragma unroll
      for (int nt = 0; nt < 8; ++nt) {
        U b; b.u = *(const uint4*)(Mth + (nt * 16 + l15) * DIM + k0);
        acc[nt] = __builtin_amdgcn_mfma_f32_16x16x32_bf16(a, b.h, acc[nt], 0, 0, 0);
      }
    }
    #pragma unroll
    for (int nt = 0; nt < 8; ++nt)
      #pragma unroll
      for (int reg = 0; reg < 4; ++reg)
        Ts[(wave * 16 + quad * 4 + reg) * TPAD + nt * 16 + l15] = f2bf(acc[nt][reg]);
    __syncthreads();
    f32x4 qacc[8];
    #pragma unroll
    for (int nt = 0; nt < 8; ++nt) qacc[nt] = f32x4{0.f, 0.f, 0.f, 0.f};
    #pragma unroll
    for (int ks = 0; ks < 4; ++ks) {
      int k0 = ks * 32 + quad * 8;
      U a; a.u = *(const uint4*)(Ts + (wave * 16 + l15) * TPAD + k0);
      #pragma unroll
      for (int nt = 0; nt < 8; ++nt) {
        const float* bp = Rr + (size_t)(nt * 16 + l15) * DIM + k0;
        float bv[8];
        *(float4*)(bv)     = *(const float4*)(bp);
        *(float4*)(bv + 4) = *(const float4*)(bp + 4);
        bf16x8 b;
        #pragma unroll
        for (int j = 0; j < 8; ++j) b[j] = (short)f2bf(bv[j]);
        qacc[nt] = __builtin_amdgcn_mfma_f32_16x16x32_bf16(a.h, b, qacc[nt], 0, 0, 0);
      }
    }
    #pragma unroll
    for (int nt = 0; nt < 8; ++nt)
      #pragma unroll
      for (int reg = 0; reg < 4; ++reg)
        Qr[(size_t)(dw + quad * 4 + reg) * DIM + nt * 16 + l15] = f2bf(qacc[nt][reg]);
  }
}

// ---------------- scan reduce + dinv ----------------

__global__ __launch_bounds__(256) void k_scanred_dinv(const int* __restrict__ cnt, int* __restrict__ bsum,
                                                      float* __restrict__ dinv) {
  __shared__ int sd[256];
  int base = blockIdx.x * 1024;
  int t = threadIdx.x;
  int s = 0;
  #pragma unroll
  for (int i = 0; i < 4; ++i) {
    int idx = base + t * 4 + i;
    if (idx < N_NODES) {
      int c = cnt[idx];
      s += c;
      dinv[idx] = rsqrtf((float)(c + 1));
    }
  }
  sd[t] = s; __syncthreads();
  for (int off = 128; off > 0; off >>= 1) {
    if (t < off) sd[t] += sd[t + off];
    __syncthreads();
  }
  if (t == 0) bsum[blockIdx.x] = sd[0];
}

__global__ void k_scan_bsum(int* __restrict__ bsum, int* __restrict__ rowptr_end, int nb) {
  if (threadIdx.x == 0 && blockIdx.x == 0) {
    int acc = 0;
    for (int i = 0; i < nb; ++i) { int v = bsum[i]; bsum[i] = acc; acc += v; }
    *rowptr_end = acc;
  }
}

__global__ __launch_bounds__(256) void k_scan_scatter(const int* __restrict__ cnt, const int* __restrict__ bsum,
                                                      int* __restrict__ rowptr) {
  __shared__ int sd[256];
  int base = blockIdx.x * 1024;
  int t = threadIdx.x;
  int v[4]; int s = 0;
  #pragma unroll
  for (int i = 0; i < 4; ++i) {
    int idx = base + t * 4 + i;
    v[i] = (idx < N_NODES) ? cnt[idx] : 0;
    s += v[i];
  }
  sd[t] = s; __syncthreads();
  for (int off = 1; off < 256; off <<= 1) {
    int y = (t >= off) ? sd[t - off] : 0;
    __syncthreads();
    sd[t] += y;
    __syncthreads();
  }
  int pre = bsum[blockIdx.x] + sd[t] - s;
  #pragma unroll
  for (int i = 0; i < 4; ++i) {
    int idx = base + t * 4 + i;
    if (idx < N_NODES) rowptr[idx] = pre;
    pre += v[i];
  }
}

// ---------------- megaB: CSR fill (no atomics)  ||  gemm1 ----------------

__global__ __launch_bounds__(256) void k_megaB(const int* __restrict__ src, const int* __restrict__ dst,
                                               const int* __restrict__ rowptr, const int* __restrict__ epos,
                                               int* __restrict__ esrc,
                                               const float* __restrict__ x,
                                               const unsigned short* __restrict__ W1th,
                                               const unsigned short* __restrict__ W1tl,
                                               unsigned short* __restrict__ hout) {
  int bid = blockIdx.x;
  union U { uint4 u; bf16x8 h; };
  if (bid < G_EDGE4) {
    int i0 = bid * 1024 + threadIdx.x * 4;
    if (i0 < N_EDGES) {
      int4 s4 = *(const int4*)(src + i0);
      int4 d4 = *(const int4*)(dst + i0);
      int4 e4 = *(const int4*)(epos + i0);
      esrc[rowptr[d4.x] + e4.x] = s4.x;
      esrc[rowptr[d4.y] + e4.y] = s4.y;
      esrc[rowptr[d4.z] + e4.z] = s4.z;
      esrc[rowptr[d4.w] + e4.w] = s4.w;
    }
  } else {
    // ---- node GEMM layer 1: hout = x @ W1 (hi/lo 3-term, bf16 out) ----
    int wave = threadIdx.x >> 6, lane = threadIdx.x & 63;
    int l15 = lane & 15, quad = lane >> 4;
    int r0 = (bid - G_EDGE4) * 128 + wave * 32;
    f32x4 acc[2][8];
    #pragma unroll
    for (int mt = 0; mt < 2; ++mt)
      #pragma unroll
      for (int nt = 0; nt < 8; ++nt) acc[mt][nt] = f32x4{0.f, 0.f, 0.f, 0.f};
    #pragma unroll
    for (int ks = 0; ks < 4; ++ks) {
      int k0 = ks * 32 + quad * 8;
      bf16x8 ah[2], al[2];
      #pragma unroll
      for (int mt = 0; mt < 2; ++mt) {
        int row = r0 + mt * 16 + l15;
        row = (row < N_NODES) ? row : (N_NODES - 1);
        const float* xp = x + (size_t)row * DIM + k0;
        float xv[8];
        *(float4*)(xv)     = *(const float4*)(xp);
        *(float4*)(xv + 4) = *(const float4*)(xp + 4);
        #pragma unroll
        for (int j = 0; j < 8; ++j) {
          unsigned short h = f2bf(xv[j]);
          ah[mt][j] = (short)h;
          al[mt][j] = (short)f2bf(xv[j] - bf2f(h));
        }
      }
      #pragma unroll
      for (int nt = 0; nt < 8; ++nt) {
        U bh, bl;
        bh.u = *(const uint4*)(W1th + (nt * 16 + l15) * DIM + k0);
        bl.u = *(const uint4*)(W1tl + (nt * 16 + l15) * DIM + k0);
        #pragma unroll
        for (int mt = 0; mt < 2; ++mt) {
          acc[mt][nt] = __builtin_amdgcn_mfma_f32_16x16x32_bf16(ah[mt], bh.h, acc[mt][nt], 0, 0, 0);
          acc[mt][nt] = __builtin_amdgcn_mfma_f32_16x16x32_bf16(al[mt], bh.h, acc[mt][nt], 0, 0, 0);
          acc[mt][nt] = __builtin_amdgcn_mfma_f32_16x16x32_bf16(ah[mt], bl.h, acc[mt][nt], 0, 0, 0);
        }
      }
    }
    #pragma unroll
    for (int mt = 0; mt < 2; ++mt)
      #pragma unroll
      for (int reg = 0; reg < 4; ++reg) {
        int row = r0 + mt * 16 + quad * 4 + reg;
        if (row < N_NODES) {
          #pragma unroll
          for (int nt = 0; nt < 8; ++nt)
            hout[(size_t)row * DIM + nt * 16 + l15] = f2bf(acc[mt][nt][reg]);
        }
      }
  }
}

// ---------------- agg: bf16 plane in -> hi/lo bf16 planes out ----------------
// out value v = dinv[d]*(sum dinv[s]h[s] + dinv[d]h[d]) + b; hi=f2bf(v), lo=f2bf(v-hi)

__global__ __launch_bounds__(256) void k_agg_hl(const unsigned short* __restrict__ h,
                                                const int* __restrict__ rowptr,
                                                const int* __restrict__ esrc, const float* __restrict__ dinv,
                                                const float* __restrict__ bias,
                                                unsigned short* __restrict__ outh,
                                                unsigned short* __restrict__ outl) {
  int node = blockIdx.x * 8 + (threadIdx.x >> 5);
  if (node >= N_NODES) return;
  int lane = threadIdx.x & 31;
  const ushort4* h4 = (const ushort4*)h;
  float di = dinv[node];
  ushort4 hv = h4[(size_t)node * 32 + lane];
  float ax = di * bf2f(hv.x), ay = di * bf2f(hv.y), az = di * bf2f(hv.z), aw = di * bf2f(hv.w);
  int e = rowptr[node], end = rowptr[node + 1];
  for (; e + 3 < end; e += 4) {
    int s0 = esrc[e], s1 = esrc[e + 1], s2 = esrc[e + 2], s3 = esrc[e + 3];
    float d0 = dinv[s0], d1 = dinv[s1], d2 = dinv[s2], d3 = dinv[s3];
    ushort4 v0 = h4[(size_t)s0 * 32 + lane];
    ushort4 v1 = h4[(size_t)s1 * 32 + lane];
    ushort4 v2 = h4[(size_t)s2 * 32 + lane];
    ushort4 v3 = h4[(size_t)s3 * 32 + lane];
    ax = fmaf(d0, bf2f(v0.x), ax); ay = fmaf(d0, bf2f(v0.y), ay); az = fmaf(d0, bf2f(v0.z), az); aw = fmaf(d0, bf2f(v0.w), aw);
    ax = fmaf(d1, bf2f(v1.x), ax); ay = fmaf(d1, bf2f(v1.y), ay); az = fmaf(d1, bf2f(v1.z), az); aw = fmaf(d1, bf2f(v1.w), aw);
    ax = fmaf(d2, bf2f(v2.x), ax); ay = fmaf(d2, bf2f(v2.y), ay); az = fmaf(d2, bf2f(v2.z), az); aw = fmaf(d2, bf2f(v2.w), aw);
    ax = fmaf(d3, bf2f(v3.x), ax); ay = fmaf(d3, bf2f(v3.y), ay); az = fmaf(d3, bf2f(v3.z), az); aw = fmaf(d3, bf2f(v3.w), aw);
  }
  for (; e < end; ++e) {
    int s = esrc[e];
    float ds = dinv[s];
    ushort4 vs = h4[(size_t)s * 32 + lane];
    ax = fmaf(ds, bf2f(vs.x), ax); ay = fmaf(ds, bf2f(vs.y), ay);
    az = fmaf(ds, bf2f(vs.z), az); aw = fmaf(ds, bf2f(vs.w), aw);
  }
  float4 bb = ((const float4*)bias)[lane];
  float vx = fmaf(di, ax, bb.x), vy = fmaf(di, ay, bb.y);
  float vz = fmaf(di, az, bb.z), vw = fmaf(di, aw, bb.w);
  ushort4 hi4, lo4;
  hi4.x = f2bf(vx); lo4.x = f2bf(vx - bf2f(hi4.x));
  hi4.y = f2bf(vy); lo4.y = f2bf(vy - bf2f(hi4.y));
  hi4.z = f2bf(vz); lo4.z = f2bf(vz - bf2f(hi4.z));
  hi4.w = f2bf(vw); lo4.w = f2bf(vw - bf2f(hi4.w));
  ((ushort4*)outh)[(size_t)node * 32 + lane] = hi4;
  ((ushort4*)outl)[(size_t)node * 32 + lane] = lo4;
}

// ---------------- gemm2: A from hi/lo planes, 3-term, bf16 out ----------------

__global__ __launch_bounds__(256) void k_gemm_hl(const unsigned short* __restrict__ xh,
                                                 const unsigned short* __restrict__ xl,
                                                 const unsigned short* __restrict__ Wth,
                                                 const unsigned short* __restrict__ Wtl,
                                                 unsigned short* __restrict__ out, int nrows) {
  int wave = threadIdx.x >> 6, lane = threadIdx.x & 63;
  int l15 = lane & 15, quad = lane >> 4;
  int r0 = blockIdx.x * 128 + wave * 32;
  f32x4 acc[2][8];
  #pragma unroll
  for (int mt = 0; mt < 2; ++mt)
    #pragma unroll
    for (int nt = 0; nt < 8; ++nt) acc[mt][nt] = f32x4{0.f, 0.f, 0.f, 0.f};
  union U { uint4 u; bf16x8 h; };
  #pragma unroll
  for (int ks = 0; ks < 4; ++ks) {
    int k0 = ks * 32 + quad * 8;
    U ah[2], al[2];
    #pragma unroll
    for (int mt = 0; mt < 2; ++mt) {
      int row = r0 + mt * 16 + l15;
      row = (row < nrows) ? row : (nrows - 1);
      ah[mt].u = *(const uint4*)(xh + (size_t)row * DIM + k0);
      al[mt].u = *(const uint4*)(xl + (size_t)row * DIM + k0);
    }
    #pragma unroll
    for (int nt = 0; nt < 8; ++nt) {
      U bh, bl;
      bh.u = *(const uint4*)(Wth + (nt * 16 + l15) * DIM + k0);
      bl.u = *(const uint4*)(Wtl + (nt * 16 + l15) * DIM + k0);
      #pragma unroll
      for (int mt = 0; mt < 2; ++mt) {
        acc[mt][nt] = __builtin_amdgcn_mfma_f32_16x16x32_bf16(ah[mt].h, bh.h, acc[mt][nt], 0, 0, 0);
        acc[mt][nt] = __builtin_amdgcn_mfma_f32_16x16x32_bf16(al[mt].h, bh.h, acc[mt][nt], 0, 0, 0);
        acc[mt][nt] = __builtin_amdgcn_mfma_f32_16x16x32_bf16(ah[mt].h, bl.h, acc[mt][nt], 0, 0, 0);
      }
    }
  }
  #pragma unroll
  for (int mt = 0; mt < 2; ++mt)
    #pragma unroll
    for (int reg = 0; reg < 4; ++reg) {
      int row = r0 + mt * 16 + quad * 4 + reg;
      if (row < nrows) {
        #pragma unroll
        for (int nt = 0; nt < 8; ++nt)
          out[(size_t)row * DIM + nt * 16 + l15] = f2bf(acc[mt][nt][reg]);
      }
    }
}

// ---------------- predict via MFMA, inline gather from hi/lo planes ----------------

#define QPAD 136

__global__ __launch_bounds__(256) void k_predict_mfma(const unsigned short* __restrict__ xh,
                                                      const unsigned short* __restrict__ xl,
                                                      const int* __restrict__ head,
                                                      const int* __restrict__ tail,
                                                      const unsigned short* __restrict__ Qbf,
                                                      float* __restrict__ out) {
  __shared__ __align__(16) unsigned short Qs[DIM * QPAD];
  __shared__ int Hidx[128];
  __shared__ int Tidx[128];
  int r = blockIdx.y;
  const unsigned short* Qr = Qbf + (size_t)r * DIM * DIM;
  for (int i = threadIdx.x; i < DIM * DIM / 8; i += 256) {
    int d = i >> 4, c = (i & 15) * 8;
    uint4 v = ((const uint4*)Qr)[i];
    *(uint4*)(&Qs[d * QPAD + c]) = v;
  }
  if (threadIdx.x < 128) Hidx[threadIdx.x] = head[blockIdx.x * 128 + threadIdx.x];
  else Tidx[threadIdx.x - 128] = tail[blockIdx.x * 128 + threadIdx.x - 128];
  __syncthreads();
  int wave = threadIdx.x >> 6, lane = threadIdx.x & 63;
  int l15 = lane & 15, quad = lane >> 4;
  int t0r = Tidx[wave * 32 + l15];
  int t1r = Tidx[wave * 32 + 16 + l15];

  f32x4 acc[2][8];
  #pragma unroll
  for (int m = 0; m < 2; ++m)
    #pragma unroll
    for (int n = 0; n < 8; ++n) acc[m][n] = f32x4{0.f, 0.f, 0.f, 0.f};

  union U { uint4 u; bf16x8 h; };
  #pragma unroll
  for (int ks = 0; ks < 4; ++ks) {
    int eoff = ks * 32 + quad * 8;
    U a0, a1;
    a0.u = *(const uint4*)(xh + (size_t)t0r * DIM + eoff);   // tail = hi plane (same as f2bf(v))
    a1.u = *(const uint4*)(xh + (size_t)t1r * DIM + eoff);
    #pragma unroll
    for (int nt = 0; nt < 8; ++nt) {
      U b; b.u = *(const uint4*)(&Qs[(nt * 16 + l15) * QPAD + eoff]);
      acc[0][nt] = __builtin_amdgcn_mfma_f32_16x16x32_bf16(a0.h, b.h, acc[0][nt], 0, 0, 0);
      acc[1][nt] = __builtin_amdgcn_mfma_f32_16x16x32_bf16(a1.h, b.h, acc[1][nt], 0, 0, 0);
    }
  }

  int bbase = blockIdx.x * 128 + wave * 32;
  #pragma unroll
  for (int m = 0; m < 2; ++m) {
    #pragma unroll
    for (int reg = 0; reg < 4; ++reg) {
      int bl = wave * 32 + m * 16 + quad * 4 + reg;
      int hrow = Hidx[bl];
      float s = 0.f;
      #pragma unroll
      for (int nt = 0; nt < 8; ++nt) {
        size_t idx = (size_t)hrow * DIM + nt * 16 + l15;
        s += (bf2f(xh[idx]) + bf2f(xl[idx])) * acc[m][nt][reg];   // head = hi+lo (fp32-grade)
      }
      #pragma unroll
      for (int off = 1; off < 16; off <<= 1) s += __shfl_xor(s, off, 64);
      if (l15 == 0) out[(size_t)(bbase + m * 16 + quad * 4 + reg) * N_REL + r] = s;
    }
  }
}

// ---------------- launch ----------------

extern "C" void kernel_launch(void* const* d_in, const int* in_sizes, int n_in,
                              void* d_out, int out_size, void* d_ws, size_t ws_size,
                              hipStream_t stream) {
  (void)in_sizes; (void)n_in; (void)out_size; (void)ws_size;
  const float* init_emb = (const float*)d_in[0];
  const float* W1  = (const float*)d_in[1];
  const float* b1  = (const float*)d_in[2];
  const float* W2  = (const float*)d_in[3];
  const float* b2  = (const float*)d_in[4];
  const float* Rel = (const float*)d_in[5];
  const float* M   = (const float*)d_in[6];
  const int* head  = (const int*)d_in[7];
  const int* tail  = (const int*)d_in[8];
  const int* src   = (const int*)d_in[9];
  const int* dst   = src + N_EDGES;
  float* out = (float*)d_out;

  char* p = (char*)d_ws;
  auto alloc = [&](size_t bytes) { char* q = p; p += (bytes + 511) & ~(size_t)511; return q; };
  int*   cnt    = (int*)alloc((size_t)N_NODES * 4);
  int*   rowptr = (int*)alloc((size_t)(N_NODES + 1) * 4);
  int*   bsum   = (int*)alloc(64 * 4);
  int*   esrc   = (int*)alloc((size_t)N_EDGES * 4);
  int*   epos   = (int*)alloc((size_t)N_EDGES * 4);
  float* dinv   = (float*)alloc((size_t)N_NODES * 4);
  unsigned short* hbuf1 = (unsigned short*)alloc((size_t)N_NODES * DIM * 2);  // gemm1 out
  unsigned short* aggh  = (unsigned short*)alloc((size_t)N_NODES * DIM * 2);  // agg1 hi
  unsigned short* aggl  = (unsigned short*)alloc((size_t)N_NODES * DIM * 2);  // agg1 lo
  unsigned short* hbuf2 = (unsigned short*)alloc((size_t)N_NODES * DIM * 2);  // gemm2 out
  unsigned short* xh    = (unsigned short*)alloc((size_t)N_NODES * DIM * 2);  // agg2 hi
  unsigned short* xl    = (unsigned short*)alloc((size_t)N_NODES * DIM * 2);  // agg2 lo
  unsigned short* Qbf   = (unsigned short*)alloc((size_t)N_REL * DIM * DIM * 2);
  unsigned short* W1th  = (unsigned short*)alloc((size_t)DIM * DIM * 2);
  unsigned short* W1tl  = (unsigned short*)alloc((size_t)DIM * DIM * 2);
  unsigned short* W2th  = (unsigned short*)alloc((size_t)DIM * DIM * 2);
  unsigned short* W2tl  = (unsigned short*)alloc((size_t)DIM * DIM * 2);
  unsigned short* Mth   = (unsigned short*)alloc((size_t)DIM * DIM * 2);

  // 0: zero cnt + weight prep
  k_prep_zero<<<256, 256, 0, stream>>>(W1, W2, M, W1th, W1tl, W2th, W2tl, Mth, cnt);
  // 1: count(+epos) || decoder TQ
  k_megaA<<<G_EDGE4 + G_TQ, 256, 0, stream>>>(dst, cnt, epos, Rel, Mth, Qbf);
  // 2-4: scan chain
  int nb = (N_NODES + 1023) / 1024;  // 49
  k_scanred_dinv<<<nb, 256, 0, stream>>>(cnt, bsum, dinv);
  k_scan_bsum<<<1, 64, 0, stream>>>(bsum, rowptr + N_NODES, nb);
  k_scan_scatter<<<nb, 256, 0, stream>>>(cnt, bsum, rowptr);
  // 5: fill (no atomics) || gemm1
  k_megaB<<<G_EDGE4 + G_GEMM, 256, 0, stream>>>(src, dst, rowptr, epos, esrc,
                                                init_emb, W1th, W1tl, hbuf1);
  // 6: agg1 -> hi/lo planes
  k_agg_hl<<<(N_NODES + 7) / 8, 256, 0, stream>>>(hbuf1, rowptr, esrc, dinv, b1, aggh, aggl);
  // 7: gemm2 from planes
  k_gemm_hl<<<(N_NODES + 127) / 128, 256, 0, stream>>>(aggh, aggl, W2th, W2tl, hbuf2, N_NODES);
  // 8: agg2 -> hi/lo planes
  k_agg_hl<<<(N_NODES + 7) / 8, 256, 0, stream>>>(hbuf2, rowptr, esrc, dinv, b2, xh, xl);
  // 9: predict (inline gather from planes)
  k_predict_mfma<<<dim3(BATCH / 128, N_REL), 256, 0, stream>>>(xh, xl, head, tail, Qbf, out);
}